// Round 1
// 859.829 us; speedup vs baseline: 1.0535x; 1.0535x over previous
//
#include <hip/hip_runtime.h>
#include <math.h>

#define NN 768
#define CSD 384
#define HD 12
#define CD 16
#define PQD 4
#define PVD 8
#define CZD 128
#define CATD 2112

// ws float offsets
#define OFF_Q      0u
#define OFF_K      147456u
#define OFF_V      294912u
#define OFF_QP     442368u
#define OFF_KP     552960u
#define OFF_VP     663552u
#define OFF_RAW    884736u
#define OFF_B      1327104u
#define OFF_A      8404992u
#define OFF_CAT    15482880u

__device__ __forceinline__ float wcol_val(const float* Wq, const float* Wkv,
                                          const float* Wqp, const float* Wkvp,
                                          int k, int col) {
  if (col < 192) return Wq[k*192 + col];
  if (col < 576) return Wkv[k*384 + (col-192)];
  if (col < 720) return Wqp[k*144 + (col-576)];
  return Wkvp[k*432 + (col-720)];
}
__device__ __forceinline__ float bias_val(const float* bq, const float* bkv,
                                          const float* bqp, const float* bkvp, int col) {
  if (col < 192) return bq[col];
  if (col < 576) return bkv[col-192];
  if (col < 720) return bqp[col-576];
  return bkvp[col-720];
}

// ---------------- K1: s @ [W_q | W_kv | W_qp | W_kvp] + bias ----------------
__global__ __launch_bounds__(256) void k_proj(const float* __restrict__ s,
    const float* __restrict__ Wq, const float* __restrict__ bq,
    const float* __restrict__ Wkv, const float* __restrict__ bkv,
    const float* __restrict__ Wqp, const float* __restrict__ bqp,
    const float* __restrict__ Wkvp, const float* __restrict__ bkvp,
    float* __restrict__ ws) {
  __shared__ float At[64*17];   // [m][k], padded
  __shared__ float Bt[16*64];   // [k][c]
  int t = threadIdx.x;
  int c0 = blockIdx.x * 64;
  int r0 = blockIdx.y * 64;
  float acc[4][4] = {};
  int cc = t & 15, rr = t >> 4;
  for (int kt = 0; kt < CSD; kt += 16) {
    int ka = t & 15, mb = t >> 4;
#pragma unroll
    for (int p = 0; p < 4; ++p) {
      int m = mb + p*16;
      At[m*17 + ka] = s[(r0+m)*CSD + kt + ka];
    }
    int cb = t & 63, kb = t >> 6;
#pragma unroll
    for (int p = 0; p < 4; ++p) {
      int kk = kb + p*4;
      Bt[kk*64 + cb] = wcol_val(Wq,Wkv,Wqp,Wkvp, kt+kk, c0+cb);
    }
    __syncthreads();
#pragma unroll
    for (int k = 0; k < 16; ++k) {
      float a0 = At[(rr*4+0)*17 + k];
      float a1 = At[(rr*4+1)*17 + k];
      float a2 = At[(rr*4+2)*17 + k];
      float a3 = At[(rr*4+3)*17 + k];
      float4 b4 = *(const float4*)&Bt[k*64 + cc*4];
      acc[0][0] = fmaf(a0,b4.x,acc[0][0]); acc[0][1] = fmaf(a0,b4.y,acc[0][1]);
      acc[0][2] = fmaf(a0,b4.z,acc[0][2]); acc[0][3] = fmaf(a0,b4.w,acc[0][3]);
      acc[1][0] = fmaf(a1,b4.x,acc[1][0]); acc[1][1] = fmaf(a1,b4.y,acc[1][1]);
      acc[1][2] = fmaf(a1,b4.z,acc[1][2]); acc[1][3] = fmaf(a1,b4.w,acc[1][3]);
      acc[2][0] = fmaf(a2,b4.x,acc[2][0]); acc[2][1] = fmaf(a2,b4.y,acc[2][1]);
      acc[2][2] = fmaf(a2,b4.z,acc[2][2]); acc[2][3] = fmaf(a2,b4.w,acc[2][3]);
      acc[3][0] = fmaf(a3,b4.x,acc[3][0]); acc[3][1] = fmaf(a3,b4.y,acc[3][1]);
      acc[3][2] = fmaf(a3,b4.z,acc[3][2]); acc[3][3] = fmaf(a3,b4.w,acc[3][3]);
    }
    __syncthreads();
  }
  float* qbuf = ws + OFF_Q; float* kbuf = ws + OFF_K; float* vbuf = ws + OFF_V;
  float* raw  = ws + OFF_RAW;
#pragma unroll
  for (int jj = 0; jj < 4; ++jj) {
    int col = c0 + cc*4 + jj;
    float bv = bias_val(bq,bkv,bqp,bkvp,col);
#pragma unroll
    for (int ii = 0; ii < 4; ++ii) {
      int row = r0 + rr*4 + ii;
      float val = acc[ii][jj] + bv;
      if (col < 192) {
        int h = col >> 4, c = col & 15;
        qbuf[(h*NN + row)*CD + c] = val;
      } else if (col < 576) {
        int u = col - 192; int h = u >> 5; int c2 = u & 31;
        if (c2 < 16) kbuf[(h*NN+row)*CD + c2] = val;
        else         vbuf[(h*NN+row)*CD + (c2-16)] = val;
      } else {
        raw[row*576 + (col-576)] = val;
      }
    }
  }
}

// ---------------- K1b: rotate+translate points ----------------
__global__ __launch_bounds__(256) void k_points(const float* __restrict__ rot,
    const float* __restrict__ trans, float* __restrict__ ws) {
  int tg = blockIdx.x*256 + threadIdx.x;      // < 768*192
  int n = tg / 192, pidx = tg % 192;
  const float* raw = ws + OFF_RAW + n*576;
  float v0, v1, v2;
  if (pidx < 48) { v0 = raw[pidx]; v1 = raw[48+pidx]; v2 = raw[96+pidx]; }
  else { int pp = pidx-48; v0 = raw[144+pp]; v1 = raw[288+pp]; v2 = raw[432+pp]; }
  const float* R = rot + n*9; const float* T = trans + n*3;
  float g0 = R[0]*v0 + R[1]*v1 + R[2]*v2 + T[0];
  float g1 = R[3]*v0 + R[4]*v1 + R[5]*v2 + T[1];
  float g2 = R[6]*v0 + R[7]*v1 + R[8]*v2 + T[2];
  if (pidx < 48) {
    int h = pidx >> 2, p = pidx & 3;
    float* qp = ws + OFF_QP + ((h*NN + n)*PQD + p)*3;
    qp[0]=g0; qp[1]=g1; qp[2]=g2;
  } else {
    int pp = pidx - 48; int h = pp/12; int q12 = pp - 12*h;
    if (q12 < 4) { float* kp = ws + OFF_KP + ((h*NN+n)*PQD + q12)*3; kp[0]=g0; kp[1]=g1; kp[2]=g2; }
    else         { float* vp = ws + OFF_VP + ((h*NN+n)*PVD + (q12-4))*3; vp[0]=g0; vp[1]=g1; vp[2]=g2; }
  }
}

// ---------------- K2 v5: bmat = sqrt(1/3)*(z @ W_b + b_b), layout (i,h,j) ----------------
// v4 was 1.72x over-fetching (64B-used of 128B lines, lane stride 512B) and
// grid-limited to 22% occupancy (576 blocks). v5: one z-row per lane, each
// c0-step reads 128B CONTIGUOUS per lane (8x float4) so every fetched line is
// fully consumed immediately; grid (192,12)=2304 blocks for full occupancy.
// Wb stays in LDS, read wave-uniform (broadcast, conflict-free).
__global__ __launch_bounds__(256) void k_bias(const float* __restrict__ z,
    const float* __restrict__ Wb, const float* __restrict__ bb, float* __restrict__ ws) {
  __shared__ float wb_sm[CZD*HD];   // [c][h], rows 48B, 16B-aligned
  __shared__ float bb_sm[HD];
  int t = threadIdx.x;
  for (int idx = t; idx < CZD*HD; idx += 256) wb_sm[idx] = Wb[idx];
  if (t < HD) bb_sm[t] = bb[t];
  __syncthreads();

  int w = t >> 6, lane = t & 63;
  int i = blockIdx.x*4 + w;
  int j = blockIdx.y*64 + lane;
  const float* zrow = z + ((size_t)i*NN + j)*CZD;
  float acc[12];
#pragma unroll
  for (int h = 0; h < 12; ++h) acc[h] = 0.f;

  for (int c0 = 0; c0 < CZD; c0 += 32) {
    float4 zr[8];
#pragma unroll
    for (int u = 0; u < 8; ++u)
      zr[u] = *(const float4*)(zrow + c0 + 4*u);
#pragma unroll
    for (int u = 0; u < 8; ++u) {
#pragma unroll
      for (int cc = 0; cc < 4; ++cc) {
        int c = c0 + 4*u + cc;
        float zv = (cc==0) ? zr[u].x : (cc==1) ? zr[u].y : (cc==2) ? zr[u].z : zr[u].w;
        float4 w0 = *(const float4*)&wb_sm[c*12];
        float4 w1 = *(const float4*)&wb_sm[c*12 + 4];
        float4 w2 = *(const float4*)&wb_sm[c*12 + 8];
        acc[0] = fmaf(zv, w0.x, acc[0]); acc[1] = fmaf(zv, w0.y, acc[1]);
        acc[2] = fmaf(zv, w0.z, acc[2]); acc[3] = fmaf(zv, w0.w, acc[3]);
        acc[4] = fmaf(zv, w1.x, acc[4]); acc[5] = fmaf(zv, w1.y, acc[5]);
        acc[6] = fmaf(zv, w1.z, acc[6]); acc[7] = fmaf(zv, w1.w, acc[7]);
        acc[8] = fmaf(zv, w2.x, acc[8]); acc[9] = fmaf(zv, w2.y, acc[9]);
        acc[10] = fmaf(zv, w2.z, acc[10]); acc[11] = fmaf(zv, w2.w, acc[11]);
      }
    }
  }
  float* bmat = ws + OFF_B;
  const float s2 = 0.57735026918962576f;
#pragma unroll
  for (int h = 0; h < 12; ++h)
    bmat[((size_t)i*HD + h)*NN + j] = s2*(acc[h] + bb_sm[h]);
}

// ---------------- K3: logits + softmax -> a (h,i,j) ----------------
__global__ __launch_bounds__(256) void k_attn(
    const float* __restrict__ mask, const float* __restrict__ ss,
    const float* __restrict__ hwts, float* __restrict__ ws) {
  int h = blockIdx.x, i = blockIdx.y;
  int t = threadIdx.x;
  __shared__ float qsm[16];
  __shared__ float qpsm[12];
  __shared__ float wred[8];
  const float* qbuf = ws + OFF_Q; const float* kbuf = ws + OFF_K;
  const float* qp   = ws + OFF_QP; const float* kp  = ws + OFF_KP;
  const float* bmat = ws + OFF_B;
  float* abuf = ws + OFF_A;
  if (t < 16) qsm[t] = qbuf[(h*NN+i)*CD + t];
  else if (t < 28) qpsm[t-16] = qp[(h*NN+i)*12 + (t-16)];
  __syncthreads();
  float coef = -0.5f * 0.13608276348795434f * log1pf(__expf(hwts[h]));
  float mi = mask[i];
  const float s1 = 0.14433756729740643f;
  float l3[3], ss3[3];
#pragma unroll
  for (int jj = 0; jj < 3; ++jj) {
    int j = t + jj*256;
    const float4* kb = (const float4*)(kbuf + (h*NN+j)*CD);
    float dot = 0.f;
#pragma unroll
    for (int u = 0; u < 4; ++u) {
      float4 kv = kb[u];
      dot = fmaf(qsm[u*4+0], kv.x, dot);
      dot = fmaf(qsm[u*4+1], kv.y, dot);
      dot = fmaf(qsm[u*4+2], kv.z, dot);
      dot = fmaf(qsm[u*4+3], kv.w, dot);
    }
    const float4* kpb = (const float4*)(kp + (h*NN+j)*12);
    float pts = 0.f;
#pragma unroll
    for (int u = 0; u < 3; ++u) {
      float4 kpv = kpb[u];
      float d;
      d = qpsm[u*4+0]-kpv.x; pts = fmaf(d,d,pts);
      d = qpsm[u*4+1]-kpv.y; pts = fmaf(d,d,pts);
      d = qpsm[u*4+2]-kpv.z; pts = fmaf(d,d,pts);
      d = qpsm[u*4+3]-kpv.w; pts = fmaf(d,d,pts);
    }
    float bterm = bmat[((size_t)i*HD + h)*NN + j];
    float lg = fmaf(dot, s1, bterm) + coef*pts + 100000.0f*(mi*mask[j] - 1.0f);
    l3[jj] = lg; ss3[jj] = ss[i*NN + j];
  }
  float mx = fmaxf(l3[0], fmaxf(l3[1], l3[2]));
#pragma unroll
  for (int off = 32; off >= 1; off >>= 1) mx = fmaxf(mx, __shfl_xor(mx, off));
  if ((t & 63) == 0) wred[t>>6] = mx;
  __syncthreads();
  mx = fmaxf(fmaxf(wred[0],wred[1]), fmaxf(wred[2],wred[3]));
  float e3[3]; float sum = 0.f;
#pragma unroll
  for (int jj = 0; jj < 3; ++jj) {
    e3[jj] = __expf(l3[jj]-mx) * (__expf(ss3[jj]) - 0.99f);
    sum += e3[jj];
  }
#pragma unroll
  for (int off = 32; off >= 1; off >>= 1) sum += __shfl_xor(sum, off);
  if ((t & 63) == 0) wred[4 + (t>>6)] = sum;
  __syncthreads();
  sum = (wred[4]+wred[5]) + (wred[6]+wred[7]);
  float inv = 1.0f / sum;
#pragma unroll
  for (int jj = 0; jj < 3; ++jj)
    abuf[((size_t)h*NN + i)*NN + t + jj*256] = e3[jj]*inv;
}

// ---------------- K4: o and o_pt (+norm) -> cat[0:576) ----------------
__global__ __launch_bounds__(256) void k_out_v(
    const float* __restrict__ rot, const float* __restrict__ trans, float* __restrict__ ws) {
  int h = blockIdx.x;
  int i = blockIdx.y*4 + (threadIdx.x >> 6);
  int lane = threadIdx.x & 63;
  const float* abuf = ws + OFF_A; const float* vbuf = ws + OFF_V; const float* vpbuf = ws + OFF_VP;
  float* cat = ws + OFF_CAT;
  const float* arow = abuf + ((size_t)h*NN + i)*NN;
  float acc = 0.f;
  if (lane < 40) {
    const float* ptr; int stride;
    if (lane < 16) { ptr = vbuf + (size_t)(h*NN)*CD + lane; stride = CD; }
    else           { ptr = vpbuf + (size_t)(h*NN)*24 + (lane-16); stride = 24; }
    for (int j = 0; j < NN; j += 4) {
      float4 a4 = *(const float4*)(arow + j);
      float x0 = ptr[0];
      float x1 = ptr[stride];
      float x2 = ptr[2*stride];
      float x3 = ptr[3*stride];
      ptr += 4*stride;
      acc = fmaf(a4.x, x0, acc);
      acc = fmaf(a4.y, x1, acc);
      acc = fmaf(a4.z, x2, acc);
      acc = fmaf(a4.w, x3, acc);
    }
  }
  if (lane < 16) {
    cat[(size_t)i*CATD + h*CD + lane] = acc;
  } else if (lane < 40) {
    int pv = lane - 16; int p = pv/3; int x = pv - 3*p;
    int base = 16 + p*3;
    float g0 = __shfl(acc, base+0);
    float g1 = __shfl(acc, base+1);
    float g2 = __shfl(acc, base+2);
    float v0 = g0 - trans[i*3+0];
    float v1 = g1 - trans[i*3+1];
    float v2 = g2 - trans[i*3+2];
    float loc = rot[i*9 + 0*3 + x]*v0 + rot[i*9 + 1*3 + x]*v1 + rot[i*9 + 2*3 + x]*v2;
    cat[(size_t)i*CATD + 192 + x*96 + h*PVD + p] = loc;
    float sq = loc*loc;
    float n2 = __shfl(sq, base+0) + __shfl(sq, base+1) + __shfl(sq, base+2);
    if (x == 0) cat[(size_t)i*CATD + 480 + h*PVD + p] = sqrtf(n2 + 1e-8f);
  }
}

// ---------------- K5 v2: o_pair = a . z -> cat[576:2112) ----------------
// a_sm reads now float4 (b128 broadcast, <=2 distinct addrs/wave) amortized
// over 4 j per step: 288 DS ops/wave/block vs ~1200 before.
__global__ __launch_bounds__(256) void k_out_pair(const float* __restrict__ z, float* __restrict__ ws) {
  __shared__ float a_sm[HD*NN];        // 36 KB
  __shared__ float4 psm[4][HD][32];    // 24 KB
  int i = blockIdx.x;
  int t = threadIdx.x;
  const float* abuf = ws + OFF_A;
  float* cat = ws + OFF_CAT;
  for (int h = 0; h < HD; ++h) {
    if (t < 192)
      *(float4*)&a_sm[h*NN + t*4] = *(const float4*)(abuf + ((size_t)h*NN + i)*NN + t*4);
  }
  __syncthreads();
  int c4 = t & 31, jc = t >> 5;     // 8 j-slices of 96; wave holds 2 slices
  const float* zbase = z + ((size_t)i*NN + (size_t)jc*96)*CZD + c4*4;
  float4 acc[12];
#pragma unroll
  for (int h = 0; h < 12; ++h) acc[h] = make_float4(0.f,0.f,0.f,0.f);
  for (int jj = 0; jj < 96; jj += 4) {
    float4 z0 = *(const float4*)(zbase + (size_t)(jj+0)*CZD);
    float4 z1 = *(const float4*)(zbase + (size_t)(jj+1)*CZD);
    float4 z2 = *(const float4*)(zbase + (size_t)(jj+2)*CZD);
    float4 z3 = *(const float4*)(zbase + (size_t)(jj+3)*CZD);
    int j0 = jc*96 + jj;
#pragma unroll
    for (int h = 0; h < 12; ++h) {
      float4 av = *(const float4*)&a_sm[h*NN + j0];
      acc[h].x = fmaf(av.x, z0.x, acc[h].x); acc[h].y = fmaf(av.x, z0.y, acc[h].y);
      acc[h].z = fmaf(av.x, z0.z, acc[h].z); acc[h].w = fmaf(av.x, z0.w, acc[h].w);
      acc[h].x = fmaf(av.y, z1.x, acc[h].x); acc[h].y = fmaf(av.y, z1.y, acc[h].y);
      acc[h].z = fmaf(av.y, z1.z, acc[h].z); acc[h].w = fmaf(av.y, z1.w, acc[h].w);
      acc[h].x = fmaf(av.z, z2.x, acc[h].x); acc[h].y = fmaf(av.z, z2.y, acc[h].y);
      acc[h].z = fmaf(av.z, z2.z, acc[h].z); acc[h].w = fmaf(av.z, z2.w, acc[h].w);
      acc[h].x = fmaf(av.w, z3.x, acc[h].x); acc[h].y = fmaf(av.w, z3.y, acc[h].y);
      acc[h].z = fmaf(av.w, z3.z, acc[h].z); acc[h].w = fmaf(av.w, z3.w, acc[h].w);
    }
  }
  int wv = t >> 6, ln = t & 63;
#pragma unroll
  for (int h = 0; h < 12; ++h) {
    acc[h].x += __shfl_down(acc[h].x, 32);
    acc[h].y += __shfl_down(acc[h].y, 32);
    acc[h].z += __shfl_down(acc[h].z, 32);
    acc[h].w += __shfl_down(acc[h].w, 32);
  }
  if (ln < 32) {
#pragma unroll
    for (int h = 0; h < 12; ++h) psm[wv][h][ln] = acc[h];
  }
  __syncthreads();
  for (int o = t; o < 384; o += 256) {
    int h = o >> 5, cc = o & 31;
    float4 s0 = psm[0][h][cc], s1 = psm[1][h][cc], s2 = psm[2][h][cc], s3 = psm[3][h][cc];
    float4 r;
    r.x = (s0.x+s1.x)+(s2.x+s3.x);
    r.y = (s0.y+s1.y)+(s2.y+s3.y);
    r.z = (s0.z+s1.z)+(s2.z+s3.z);
    r.w = (s0.w+s1.w)+(s2.w+s3.w);
    *(float4*)&cat[(size_t)i*CATD + 576 + h*CZD + cc*4] = r;
  }
}

// ---------------- K6: out = cat @ W_out + b_out ----------------
__global__ __launch_bounds__(256) void k_init_out(const float* __restrict__ bout, float* __restrict__ out) {
  int idx = blockIdx.x*256 + threadIdx.x;
  if (idx < NN*CSD) out[idx] = bout[idx % CSD];
}

__global__ __launch_bounds__(256) void k_final(const float* __restrict__ Wout,
    float* __restrict__ out, const float* __restrict__ ws) {
  __shared__ float At[64*17];
  __shared__ float Bt[16*64];
  const float* cat = ws + OFF_CAT;
  int t = threadIdx.x;
  int c0 = blockIdx.x*64, r0 = blockIdx.y*64;
  int kstart = blockIdx.z*528;
  float acc[4][4] = {};
  int cc = t & 15, rr = t >> 4;
  for (int kt = 0; kt < 528; kt += 16) {
    int ka = t & 15, mb = t >> 4;
#pragma unroll
    for (int p = 0; p < 4; ++p) {
      int m = mb + p*16;
      At[m*17 + ka] = cat[(size_t)(r0+m)*CATD + kstart + kt + ka];
    }
    int cb = t & 63, kb = t >> 6;
#pragma unroll
    for (int p = 0; p < 4; ++p) {
      int kk = kb + p*4;
      Bt[kk*64 + cb] = Wout[(size_t)(kstart+kt+kk)*CSD + c0 + cb];
    }
    __syncthreads();
#pragma unroll
    for (int k = 0; k < 16; ++k) {
      float a0 = At[(rr*4+0)*17 + k];
      float a1 = At[(rr*4+1)*17 + k];
      float a2 = At[(rr*4+2)*17 + k];
      float a3 = At[(rr*4+3)*17 + k];
      float4 b4 = *(const float4*)&Bt[k*64 + cc*4];
      acc[0][0] = fmaf(a0,b4.x,acc[0][0]); acc[0][1] = fmaf(a0,b4.y,acc[0][1]);
      acc[0][2] = fmaf(a0,b4.z,acc[0][2]); acc[0][3] = fmaf(a0,b4.w,acc[0][3]);
      acc[1][0] = fmaf(a1,b4.x,acc[1][0]); acc[1][1] = fmaf(a1,b4.y,acc[1][1]);
      acc[1][2] = fmaf(a1,b4.z,acc[1][2]); acc[1][3] = fmaf(a1,b4.w,acc[1][3]);
      acc[2][0] = fmaf(a2,b4.x,acc[2][0]); acc[2][1] = fmaf(a2,b4.y,acc[2][1]);
      acc[2][2] = fmaf(a2,b4.z,acc[2][2]); acc[2][3] = fmaf(a2,b4.w,acc[2][3]);
      acc[3][0] = fmaf(a3,b4.x,acc[3][0]); acc[3][1] = fmaf(a3,b4.y,acc[3][1]);
      acc[3][2] = fmaf(a3,b4.z,acc[3][2]); acc[3][3] = fmaf(a3,b4.w,acc[3][3]);
    }
    __syncthreads();
  }
#pragma unroll
  for (int ii = 0; ii < 4; ++ii)
#pragma unroll
    for (int jj = 0; jj < 4; ++jj)
      atomicAdd(&out[(size_t)(r0+rr*4+ii)*CSD + c0 + cc*4 + jj], acc[ii][jj]);
}

extern "C" void kernel_launch(void* const* d_in, const int* in_sizes, int n_in,
                              void* d_out, int out_size, void* d_ws, size_t ws_size,
                              hipStream_t stream) {
  const float* s    = (const float*)d_in[0];
  const float* z    = (const float*)d_in[1];
  const float* rot  = (const float*)d_in[2];
  const float* trans= (const float*)d_in[3];
  const float* mask = (const float*)d_in[4];
  const float* ss   = (const float*)d_in[5];
  const float* Wq   = (const float*)d_in[6];
  const float* bq   = (const float*)d_in[7];
  const float* Wkv  = (const float*)d_in[8];
  const float* bkv  = (const float*)d_in[9];
  const float* Wqp  = (const float*)d_in[10];
  const float* bqp  = (const float*)d_in[11];
  const float* Wkvp = (const float*)d_in[12];
  const float* bkvp = (const float*)d_in[13];
  const float* Wb   = (const float*)d_in[14];
  const float* bb   = (const float*)d_in[15];
  const float* hw   = (const float*)d_in[16];
  const float* Wout = (const float*)d_in[17];
  const float* bout = (const float*)d_in[18];
  float* ws  = (float*)d_ws;
  float* out = (float*)d_out;

  hipLaunchKernelGGL(k_proj, dim3(18,12), dim3(256), 0, stream,
                     s, Wq,bq, Wkv,bkv, Wqp,bqp, Wkvp,bkvp, ws);
  hipLaunchKernelGGL(k_points, dim3(576), dim3(256), 0, stream, rot, trans, ws);
  hipLaunchKernelGGL(k_bias, dim3(192,12), dim3(256), 0, stream, z, Wb, bb, ws);
  hipLaunchKernelGGL(k_attn, dim3(12,768), dim3(256), 0, stream, mask, ss, hw, ws);
  hipLaunchKernelGGL(k_out_v, dim3(12,192), dim3(256), 0, stream, rot, trans, ws);
  hipLaunchKernelGGL(k_out_pair, dim3(768), dim3(256), 0, stream, z, ws);
  hipLaunchKernelGGL(k_init_out, dim3(1152), dim3(256), 0, stream, bout, out);
  hipLaunchKernelGGL(k_final, dim3(6,12,4), dim3(256), 0, stream, Wout, out, ws);
}

// Round 2
// 849.152 us; speedup vs baseline: 1.0667x; 1.0126x over previous
//
#include <hip/hip_runtime.h>
#include <math.h>

#define NN 768
#define CSD 384
#define HD 12
#define CD 16
#define PQD 4
#define PVD 8
#define CZD 128
#define CATD 2112

// ws float offsets
#define OFF_Q      0u
#define OFF_K      147456u
#define OFF_V      294912u
#define OFF_QP     442368u
#define OFF_KP     552960u
#define OFF_VP     663552u
#define OFF_RAW    884736u
#define OFF_B      1327104u
#define OFF_A      8404992u
#define OFF_CAT    15482880u

__device__ __forceinline__ float wcol_val(const float* Wq, const float* Wkv,
                                          const float* Wqp, const float* Wkvp,
                                          int k, int col) {
  if (col < 192) return Wq[k*192 + col];
  if (col < 576) return Wkv[k*384 + (col-192)];
  if (col < 720) return Wqp[k*144 + (col-576)];
  return Wkvp[k*432 + (col-720)];
}
__device__ __forceinline__ float bias_val(const float* bq, const float* bkv,
                                          const float* bqp, const float* bkvp, int col) {
  if (col < 192) return bq[col];
  if (col < 576) return bkv[col-192];
  if (col < 720) return bqp[col-576];
  return bkvp[col-720];
}

// ---------------- K1: s @ [W_q | W_kv | W_qp | W_kvp] + bias ----------------
__global__ __launch_bounds__(256) void k_proj(const float* __restrict__ s,
    const float* __restrict__ Wq, const float* __restrict__ bq,
    const float* __restrict__ Wkv, const float* __restrict__ bkv,
    const float* __restrict__ Wqp, const float* __restrict__ bqp,
    const float* __restrict__ Wkvp, const float* __restrict__ bkvp,
    float* __restrict__ ws) {
  __shared__ float At[64*17];   // [m][k], padded
  __shared__ float Bt[16*64];   // [k][c]
  int t = threadIdx.x;
  int c0 = blockIdx.x * 64;
  int r0 = blockIdx.y * 64;
  float acc[4][4] = {};
  int cc = t & 15, rr = t >> 4;
  for (int kt = 0; kt < CSD; kt += 16) {
    int ka = t & 15, mb = t >> 4;
#pragma unroll
    for (int p = 0; p < 4; ++p) {
      int m = mb + p*16;
      At[m*17 + ka] = s[(r0+m)*CSD + kt + ka];
    }
    int cb = t & 63, kb = t >> 6;
#pragma unroll
    for (int p = 0; p < 4; ++p) {
      int kk = kb + p*4;
      Bt[kk*64 + cb] = wcol_val(Wq,Wkv,Wqp,Wkvp, kt+kk, c0+cb);
    }
    __syncthreads();
#pragma unroll
    for (int k = 0; k < 16; ++k) {
      float a0 = At[(rr*4+0)*17 + k];
      float a1 = At[(rr*4+1)*17 + k];
      float a2 = At[(rr*4+2)*17 + k];
      float a3 = At[(rr*4+3)*17 + k];
      float4 b4 = *(const float4*)&Bt[k*64 + cc*4];
      acc[0][0] = fmaf(a0,b4.x,acc[0][0]); acc[0][1] = fmaf(a0,b4.y,acc[0][1]);
      acc[0][2] = fmaf(a0,b4.z,acc[0][2]); acc[0][3] = fmaf(a0,b4.w,acc[0][3]);
      acc[1][0] = fmaf(a1,b4.x,acc[1][0]); acc[1][1] = fmaf(a1,b4.y,acc[1][1]);
      acc[1][2] = fmaf(a1,b4.z,acc[1][2]); acc[1][3] = fmaf(a1,b4.w,acc[1][3]);
      acc[2][0] = fmaf(a2,b4.x,acc[2][0]); acc[2][1] = fmaf(a2,b4.y,acc[2][1]);
      acc[2][2] = fmaf(a2,b4.z,acc[2][2]); acc[2][3] = fmaf(a2,b4.w,acc[2][3]);
      acc[3][0] = fmaf(a3,b4.x,acc[3][0]); acc[3][1] = fmaf(a3,b4.y,acc[3][1]);
      acc[3][2] = fmaf(a3,b4.z,acc[3][2]); acc[3][3] = fmaf(a3,b4.w,acc[3][3]);
    }
    __syncthreads();
  }
  float* qbuf = ws + OFF_Q; float* kbuf = ws + OFF_K; float* vbuf = ws + OFF_V;
  float* raw  = ws + OFF_RAW;
#pragma unroll
  for (int jj = 0; jj < 4; ++jj) {
    int col = c0 + cc*4 + jj;
    float bv = bias_val(bq,bkv,bqp,bkvp,col);
#pragma unroll
    for (int ii = 0; ii < 4; ++ii) {
      int row = r0 + rr*4 + ii;
      float val = acc[ii][jj] + bv;
      if (col < 192) {
        int h = col >> 4, c = col & 15;
        qbuf[(h*NN + row)*CD + c] = val;
      } else if (col < 576) {
        int u = col - 192; int h = u >> 5; int c2 = u & 31;
        if (c2 < 16) kbuf[(h*NN+row)*CD + c2] = val;
        else         vbuf[(h*NN+row)*CD + (c2-16)] = val;
      } else {
        raw[row*576 + (col-576)] = val;
      }
    }
  }
}

// ---------------- K1b: rotate+translate points ----------------
__global__ __launch_bounds__(256) void k_points(const float* __restrict__ rot,
    const float* __restrict__ trans, float* __restrict__ ws) {
  int tg = blockIdx.x*256 + threadIdx.x;      // < 768*192
  int n = tg / 192, pidx = tg % 192;
  const float* raw = ws + OFF_RAW + n*576;
  float v0, v1, v2;
  if (pidx < 48) { v0 = raw[pidx]; v1 = raw[48+pidx]; v2 = raw[96+pidx]; }
  else { int pp = pidx-48; v0 = raw[144+pp]; v1 = raw[288+pp]; v2 = raw[432+pp]; }
  const float* R = rot + n*9; const float* T = trans + n*3;
  float g0 = R[0]*v0 + R[1]*v1 + R[2]*v2 + T[0];
  float g1 = R[3]*v0 + R[4]*v1 + R[5]*v2 + T[1];
  float g2 = R[6]*v0 + R[7]*v1 + R[8]*v2 + T[2];
  if (pidx < 48) {
    int h = pidx >> 2, p = pidx & 3;
    float* qp = ws + OFF_QP + ((h*NN + n)*PQD + p)*3;
    qp[0]=g0; qp[1]=g1; qp[2]=g2;
  } else {
    int pp = pidx - 48; int h = pp/12; int q12 = pp - 12*h;
    if (q12 < 4) { float* kp = ws + OFF_KP + ((h*NN+n)*PQD + q12)*3; kp[0]=g0; kp[1]=g1; kp[2]=g2; }
    else         { float* vp = ws + OFF_VP + ((h*NN+n)*PVD + (q12-4))*3; vp[0]=g0; vp[1]=g1; vp[2]=g2; }
  }
}

// ---------------- K2 v6: bmat = sqrt(1/3)*(z @ W_b + b_b), layout (i,h,j) ----------------
// v5 (one full z-row per lane) was still 159us: every VMEM instr touched 64
// distinct 128B lines (512B lane stride) and the 8-instr completion window
// blew the 32KB L1 (36 waves x 8KB), causing 8x L1/L2 transaction
// amplification. v6: thread (q=t&15) owns c in [8q,8q+8); 16 q-lanes tile a
// full 512B row per instr (16 lines/instr, each line completed by the very
// next instr -> L1 hit). Wb slice lives in 96 VGPRs (no LDS, no barriers);
// partial acc reduced across the 16 q-lanes via shfl_xor. Depth-2 register
// prefetch; 1152 blocks x 256 thr; rows r = base + g + 16*s (g=t>>4 global
// across the block's 4 waves, s=0..31 -> 512 rows/block).
__global__ __launch_bounds__(256) void k_bias(const float* __restrict__ z,
    const float* __restrict__ Wb, const float* __restrict__ bb, float* __restrict__ ws) {
  int t = threadIdx.x;
  int q = t & 15, g = t >> 4;
  float wbr[8][12];
#pragma unroll
  for (int cc = 0; cc < 8; ++cc) {
    const float* wp = Wb + (q*8 + cc)*HD;
#pragma unroll
    for (int h = 0; h < 12; ++h) wbr[cc][h] = wp[h];
  }
  float bbr[12];
#pragma unroll
  for (int h = 0; h < 12; ++h) bbr[h] = bb[h];

  const int base = blockIdx.x * 512;
  const float* zq = z + (size_t)(base + g)*CZD + q*8;
  float4 p0a = *(const float4*)(zq);
  float4 p0b = *(const float4*)(zq + 4);
  float4 p1a = *(const float4*)(zq + 16*CZD);
  float4 p1b = *(const float4*)(zq + 16*CZD + 4);
  float* bmat = ws + OFF_B;
  const float s2 = 0.57735026918962576f;
  for (int s = 0; s < 32; ++s) {
    float4 za = p0a, zb = p0b;
    p0a = p1a; p0b = p1b;
    if (s < 30) {
      p1a = *(const float4*)(zq + (size_t)(s+2)*16*CZD);
      p1b = *(const float4*)(zq + (size_t)(s+2)*16*CZD + 4);
    }
    float acc[12];
#pragma unroll
    for (int h = 0; h < 12; ++h) acc[h] = 0.f;
#pragma unroll
    for (int h = 0; h < 12; ++h) {
      acc[h] = fmaf(za.x, wbr[0][h], acc[h]);
      acc[h] = fmaf(za.y, wbr[1][h], acc[h]);
      acc[h] = fmaf(za.z, wbr[2][h], acc[h]);
      acc[h] = fmaf(za.w, wbr[3][h], acc[h]);
      acc[h] = fmaf(zb.x, wbr[4][h], acc[h]);
      acc[h] = fmaf(zb.y, wbr[5][h], acc[h]);
      acc[h] = fmaf(zb.z, wbr[6][h], acc[h]);
      acc[h] = fmaf(zb.w, wbr[7][h], acc[h]);
    }
#pragma unroll
    for (int off = 8; off >= 1; off >>= 1)
#pragma unroll
      for (int h = 0; h < 12; ++h) acc[h] += __shfl_xor(acc[h], off);
    if (q == 0) {
      int r = base + g + 16*s;
      int i = r / NN;
      int j = r - i*NN;
#pragma unroll
      for (int h = 0; h < 12; ++h)
        bmat[((size_t)i*HD + h)*NN + j] = s2*(acc[h] + bbr[h]);
    }
  }
}

// ---------------- K3: logits + softmax -> a (h,i,j) ----------------
__global__ __launch_bounds__(256) void k_attn(
    const float* __restrict__ mask, const float* __restrict__ ss,
    const float* __restrict__ hwts, float* __restrict__ ws) {
  int h = blockIdx.x, i = blockIdx.y;
  int t = threadIdx.x;
  __shared__ float qsm[16];
  __shared__ float qpsm[12];
  __shared__ float wred[8];
  const float* qbuf = ws + OFF_Q; const float* kbuf = ws + OFF_K;
  const float* qp   = ws + OFF_QP; const float* kp  = ws + OFF_KP;
  const float* bmat = ws + OFF_B;
  float* abuf = ws + OFF_A;
  if (t < 16) qsm[t] = qbuf[(h*NN+i)*CD + t];
  else if (t < 28) qpsm[t-16] = qp[(h*NN+i)*12 + (t-16)];
  __syncthreads();
  float coef = -0.5f * 0.13608276348795434f * log1pf(__expf(hwts[h]));
  float mi = mask[i];
  const float s1 = 0.14433756729740643f;
  float l3[3], ss3[3];
#pragma unroll
  for (int jj = 0; jj < 3; ++jj) {
    int j = t + jj*256;
    const float4* kb = (const float4*)(kbuf + (h*NN+j)*CD);
    float dot = 0.f;
#pragma unroll
    for (int u = 0; u < 4; ++u) {
      float4 kv = kb[u];
      dot = fmaf(qsm[u*4+0], kv.x, dot);
      dot = fmaf(qsm[u*4+1], kv.y, dot);
      dot = fmaf(qsm[u*4+2], kv.z, dot);
      dot = fmaf(qsm[u*4+3], kv.w, dot);
    }
    const float4* kpb = (const float4*)(kp + (h*NN+j)*12);
    float pts = 0.f;
#pragma unroll
    for (int u = 0; u < 3; ++u) {
      float4 kpv = kpb[u];
      float d;
      d = qpsm[u*4+0]-kpv.x; pts = fmaf(d,d,pts);
      d = qpsm[u*4+1]-kpv.y; pts = fmaf(d,d,pts);
      d = qpsm[u*4+2]-kpv.z; pts = fmaf(d,d,pts);
      d = qpsm[u*4+3]-kpv.w; pts = fmaf(d,d,pts);
    }
    float bterm = bmat[((size_t)i*HD + h)*NN + j];
    float lg = fmaf(dot, s1, bterm) + coef*pts + 100000.0f*(mi*mask[j] - 1.0f);
    l3[jj] = lg; ss3[jj] = ss[i*NN + j];
  }
  float mx = fmaxf(l3[0], fmaxf(l3[1], l3[2]));
#pragma unroll
  for (int off = 32; off >= 1; off >>= 1) mx = fmaxf(mx, __shfl_xor(mx, off));
  if ((t & 63) == 0) wred[t>>6] = mx;
  __syncthreads();
  mx = fmaxf(fmaxf(wred[0],wred[1]), fmaxf(wred[2],wred[3]));
  float e3[3]; float sum = 0.f;
#pragma unroll
  for (int jj = 0; jj < 3; ++jj) {
    e3[jj] = __expf(l3[jj]-mx) * (__expf(ss3[jj]) - 0.99f);
    sum += e3[jj];
  }
#pragma unroll
  for (int off = 32; off >= 1; off >>= 1) sum += __shfl_xor(sum, off);
  if ((t & 63) == 0) wred[4 + (t>>6)] = sum;
  __syncthreads();
  sum = (wred[4]+wred[5]) + (wred[6]+wred[7]);
  float inv = 1.0f / sum;
#pragma unroll
  for (int jj = 0; jj < 3; ++jj)
    abuf[((size_t)h*NN + i)*NN + t + jj*256] = e3[jj]*inv;
}

// ---------------- K4: o and o_pt (+norm) -> cat[0:576) ----------------
__global__ __launch_bounds__(256) void k_out_v(
    const float* __restrict__ rot, const float* __restrict__ trans, float* __restrict__ ws) {
  int h = blockIdx.x;
  int i = blockIdx.y*4 + (threadIdx.x >> 6);
  int lane = threadIdx.x & 63;
  const float* abuf = ws + OFF_A; const float* vbuf = ws + OFF_V; const float* vpbuf = ws + OFF_VP;
  float* cat = ws + OFF_CAT;
  const float* arow = abuf + ((size_t)h*NN + i)*NN;
  float acc = 0.f;
  if (lane < 40) {
    const float* ptr; int stride;
    if (lane < 16) { ptr = vbuf + (size_t)(h*NN)*CD + lane; stride = CD; }
    else           { ptr = vpbuf + (size_t)(h*NN)*24 + (lane-16); stride = 24; }
    for (int j = 0; j < NN; j += 4) {
      float4 a4 = *(const float4*)(arow + j);
      float x0 = ptr[0];
      float x1 = ptr[stride];
      float x2 = ptr[2*stride];
      float x3 = ptr[3*stride];
      ptr += 4*stride;
      acc = fmaf(a4.x, x0, acc);
      acc = fmaf(a4.y, x1, acc);
      acc = fmaf(a4.z, x2, acc);
      acc = fmaf(a4.w, x3, acc);
    }
  }
  if (lane < 16) {
    cat[(size_t)i*CATD + h*CD + lane] = acc;
  } else if (lane < 40) {
    int pv = lane - 16; int p = pv/3; int x = pv - 3*p;
    int base = 16 + p*3;
    float g0 = __shfl(acc, base+0);
    float g1 = __shfl(acc, base+1);
    float g2 = __shfl(acc, base+2);
    float v0 = g0 - trans[i*3+0];
    float v1 = g1 - trans[i*3+1];
    float v2 = g2 - trans[i*3+2];
    float loc = rot[i*9 + 0*3 + x]*v0 + rot[i*9 + 1*3 + x]*v1 + rot[i*9 + 2*3 + x]*v2;
    cat[(size_t)i*CATD + 192 + x*96 + h*PVD + p] = loc;
    float sq = loc*loc;
    float n2 = __shfl(sq, base+0) + __shfl(sq, base+1) + __shfl(sq, base+2);
    if (x == 0) cat[(size_t)i*CATD + 480 + h*PVD + p] = sqrtf(n2 + 1e-8f);
  }
}

// ---------------- K5 v2: o_pair = a . z -> cat[576:2112) ----------------
__global__ __launch_bounds__(256) void k_out_pair(const float* __restrict__ z, float* __restrict__ ws) {
  __shared__ float a_sm[HD*NN];        // 36 KB
  __shared__ float4 psm[4][HD][32];    // 24 KB
  int i = blockIdx.x;
  int t = threadIdx.x;
  const float* abuf = ws + OFF_A;
  float* cat = ws + OFF_CAT;
  for (int h = 0; h < HD; ++h) {
    if (t < 192)
      *(float4*)&a_sm[h*NN + t*4] = *(const float4*)(abuf + ((size_t)h*NN + i)*NN + t*4);
  }
  __syncthreads();
  int c4 = t & 31, jc = t >> 5;     // 8 j-slices of 96; wave holds 2 slices
  const float* zbase = z + ((size_t)i*NN + (size_t)jc*96)*CZD + c4*4;
  float4 acc[12];
#pragma unroll
  for (int h = 0; h < 12; ++h) acc[h] = make_float4(0.f,0.f,0.f,0.f);
  for (int jj = 0; jj < 96; jj += 4) {
    float4 z0 = *(const float4*)(zbase + (size_t)(jj+0)*CZD);
    float4 z1 = *(const float4*)(zbase + (size_t)(jj+1)*CZD);
    float4 z2 = *(const float4*)(zbase + (size_t)(jj+2)*CZD);
    float4 z3 = *(const float4*)(zbase + (size_t)(jj+3)*CZD);
    int j0 = jc*96 + jj;
#pragma unroll
    for (int h = 0; h < 12; ++h) {
      float4 av = *(const float4*)&a_sm[h*NN + j0];
      acc[h].x = fmaf(av.x, z0.x, acc[h].x); acc[h].y = fmaf(av.x, z0.y, acc[h].y);
      acc[h].z = fmaf(av.x, z0.z, acc[h].z); acc[h].w = fmaf(av.x, z0.w, acc[h].w);
      acc[h].x = fmaf(av.y, z1.x, acc[h].x); acc[h].y = fmaf(av.y, z1.y, acc[h].y);
      acc[h].z = fmaf(av.y, z1.z, acc[h].z); acc[h].w = fmaf(av.y, z1.w, acc[h].w);
      acc[h].x = fmaf(av.z, z2.x, acc[h].x); acc[h].y = fmaf(av.z, z2.y, acc[h].y);
      acc[h].z = fmaf(av.z, z2.z, acc[h].z); acc[h].w = fmaf(av.z, z2.w, acc[h].w);
      acc[h].x = fmaf(av.w, z3.x, acc[h].x); acc[h].y = fmaf(av.w, z3.y, acc[h].y);
      acc[h].z = fmaf(av.w, z3.z, acc[h].z); acc[h].w = fmaf(av.w, z3.w, acc[h].w);
    }
  }
  int wv = t >> 6, ln = t & 63;
#pragma unroll
  for (int h = 0; h < 12; ++h) {
    acc[h].x += __shfl_down(acc[h].x, 32);
    acc[h].y += __shfl_down(acc[h].y, 32);
    acc[h].z += __shfl_down(acc[h].z, 32);
    acc[h].w += __shfl_down(acc[h].w, 32);
  }
  if (ln < 32) {
#pragma unroll
    for (int h = 0; h < 12; ++h) psm[wv][h][ln] = acc[h];
  }
  __syncthreads();
  for (int o = t; o < 384; o += 256) {
    int h = o >> 5, cc = o & 31;
    float4 s0 = psm[0][h][cc], s1 = psm[1][h][cc], s2 = psm[2][h][cc], s3 = psm[3][h][cc];
    float4 r;
    r.x = (s0.x+s1.x)+(s2.x+s3.x);
    r.y = (s0.y+s1.y)+(s2.y+s3.y);
    r.z = (s0.z+s1.z)+(s2.z+s3.z);
    r.w = (s0.w+s1.w)+(s2.w+s3.w);
    *(float4*)&cat[(size_t)i*CATD + 576 + h*CZD + cc*4] = r;
  }
}

// ---------------- K6: out = cat @ W_out + b_out ----------------
__global__ __launch_bounds__(256) void k_init_out(const float* __restrict__ bout, float* __restrict__ out) {
  int idx = blockIdx.x*256 + threadIdx.x;
  if (idx < NN*CSD) out[idx] = bout[idx % CSD];
}

__global__ __launch_bounds__(256) void k_final(const float* __restrict__ Wout,
    float* __restrict__ out, const float* __restrict__ ws) {
  __shared__ float At[64*17];
  __shared__ float Bt[16*64];
  const float* cat = ws + OFF_CAT;
  int t = threadIdx.x;
  int c0 = blockIdx.x*64, r0 = blockIdx.y*64;
  int kstart = blockIdx.z*528;
  float acc[4][4] = {};
  int cc = t & 15, rr = t >> 4;
  for (int kt = 0; kt < 528; kt += 16) {
    int ka = t & 15, mb = t >> 4;
#pragma unroll
    for (int p = 0; p < 4; ++p) {
      int m = mb + p*16;
      At[m*17 + ka] = cat[(size_t)(r0+m)*CATD + kstart + kt + ka];
    }
    int cb = t & 63, kb = t >> 6;
#pragma unroll
    for (int p = 0; p < 4; ++p) {
      int kk = kb + p*4;
      Bt[kk*64 + cb] = Wout[(size_t)(kstart+kt+kk)*CSD + c0 + cb];
    }
    __syncthreads();
#pragma unroll
    for (int k = 0; k < 16; ++k) {
      float a0 = At[(rr*4+0)*17 + k];
      float a1 = At[(rr*4+1)*17 + k];
      float a2 = At[(rr*4+2)*17 + k];
      float a3 = At[(rr*4+3)*17 + k];
      float4 b4 = *(const float4*)&Bt[k*64 + cc*4];
      acc[0][0] = fmaf(a0,b4.x,acc[0][0]); acc[0][1] = fmaf(a0,b4.y,acc[0][1]);
      acc[0][2] = fmaf(a0,b4.z,acc[0][2]); acc[0][3] = fmaf(a0,b4.w,acc[0][3]);
      acc[1][0] = fmaf(a1,b4.x,acc[1][0]); acc[1][1] = fmaf(a1,b4.y,acc[1][1]);
      acc[1][2] = fmaf(a1,b4.z,acc[1][2]); acc[1][3] = fmaf(a1,b4.w,acc[1][3]);
      acc[2][0] = fmaf(a2,b4.x,acc[2][0]); acc[2][1] = fmaf(a2,b4.y,acc[2][1]);
      acc[2][2] = fmaf(a2,b4.z,acc[2][2]); acc[2][3] = fmaf(a2,b4.w,acc[2][3]);
      acc[3][0] = fmaf(a3,b4.x,acc[3][0]); acc[3][1] = fmaf(a3,b4.y,acc[3][1]);
      acc[3][2] = fmaf(a3,b4.z,acc[3][2]); acc[3][3] = fmaf(a3,b4.w,acc[3][3]);
    }
    __syncthreads();
  }
#pragma unroll
  for (int ii = 0; ii < 4; ++ii)
#pragma unroll
    for (int jj = 0; jj < 4; ++jj)
      atomicAdd(&out[(size_t)(r0+rr*4+ii)*CSD + c0 + cc*4 + jj], acc[ii][jj]);
}

extern "C" void kernel_launch(void* const* d_in, const int* in_sizes, int n_in,
                              void* d_out, int out_size, void* d_ws, size_t ws_size,
                              hipStream_t stream) {
  const float* s    = (const float*)d_in[0];
  const float* z    = (const float*)d_in[1];
  const float* rot  = (const float*)d_in[2];
  const float* trans= (const float*)d_in[3];
  const float* mask = (const float*)d_in[4];
  const float* ss   = (const float*)d_in[5];
  const float* Wq   = (const float*)d_in[6];
  const float* bq   = (const float*)d_in[7];
  const float* Wkv  = (const float*)d_in[8];
  const float* bkv  = (const float*)d_in[9];
  const float* Wqp  = (const float*)d_in[10];
  const float* bqp  = (const float*)d_in[11];
  const float* Wkvp = (const float*)d_in[12];
  const float* bkvp = (const float*)d_in[13];
  const float* Wb   = (const float*)d_in[14];
  const float* bb   = (const float*)d_in[15];
  const float* hw   = (const float*)d_in[16];
  const float* Wout = (const float*)d_in[17];
  const float* bout = (const float*)d_in[18];
  float* ws  = (float*)d_ws;
  float* out = (float*)d_out;

  hipLaunchKernelGGL(k_proj, dim3(18,12), dim3(256), 0, stream,
                     s, Wq,bq, Wkv,bkv, Wqp,bqp, Wkvp,bkvp, ws);
  hipLaunchKernelGGL(k_points, dim3(576), dim3(256), 0, stream, rot, trans, ws);
  hipLaunchKernelGGL(k_bias, dim3(1152), dim3(256), 0, stream, z, Wb, bb, ws);
  hipLaunchKernelGGL(k_attn, dim3(12,768), dim3(256), 0, stream, mask, ss, hw, ws);
  hipLaunchKernelGGL(k_out_v, dim3(12,192), dim3(256), 0, stream, rot, trans, ws);
  hipLaunchKernelGGL(k_out_pair, dim3(768), dim3(256), 0, stream, z, ws);
  hipLaunchKernelGGL(k_init_out, dim3(1152), dim3(256), 0, stream, bout, out);
  hipLaunchKernelGGL(k_final, dim3(6,12,4), dim3(256), 0, stream, Wout, out, ws);
}

// Round 3
// 829.072 us; speedup vs baseline: 1.0925x; 1.0242x over previous
//
#include <hip/hip_runtime.h>
#include <math.h>

#define NN 768
#define CSD 384
#define HD 12
#define CD 16
#define PQD 4
#define PVD 8
#define CZD 128
#define CATD 2112

// ws float offsets
#define OFF_Q      0u
#define OFF_K      147456u
#define OFF_V      294912u
#define OFF_QP     442368u
#define OFF_KP     552960u
#define OFF_VP     663552u
#define OFF_RAW    884736u
#define OFF_B      1327104u
#define OFF_A      8404992u
#define OFF_CAT    15482880u

__device__ __forceinline__ float wcol_val(const float* Wq, const float* Wkv,
                                          const float* Wqp, const float* Wkvp,
                                          int k, int col) {
  if (col < 192) return Wq[k*192 + col];
  if (col < 576) return Wkv[k*384 + (col-192)];
  if (col < 720) return Wqp[k*144 + (col-576)];
  return Wkvp[k*432 + (col-720)];
}
__device__ __forceinline__ float bias_val(const float* bq, const float* bkv,
                                          const float* bqp, const float* bkvp, int col) {
  if (col < 192) return bq[col];
  if (col < 576) return bkv[col-192];
  if (col < 720) return bqp[col-576];
  return bkvp[col-720];
}

// ---------------- K1: s @ [W_q | W_kv | W_qp | W_kvp] + bias ----------------
__global__ __launch_bounds__(256) void k_proj(const float* __restrict__ s,
    const float* __restrict__ Wq, const float* __restrict__ bq,
    const float* __restrict__ Wkv, const float* __restrict__ bkv,
    const float* __restrict__ Wqp, const float* __restrict__ bqp,
    const float* __restrict__ Wkvp, const float* __restrict__ bkvp,
    float* __restrict__ ws) {
  __shared__ float At[64*17];   // [m][k], padded
  __shared__ float Bt[16*64];   // [k][c]
  int t = threadIdx.x;
  int c0 = blockIdx.x * 64;
  int r0 = blockIdx.y * 64;
  float acc[4][4] = {};
  int cc = t & 15, rr = t >> 4;
  for (int kt = 0; kt < CSD; kt += 16) {
    int ka = t & 15, mb = t >> 4;
#pragma unroll
    for (int p = 0; p < 4; ++p) {
      int m = mb + p*16;
      At[m*17 + ka] = s[(r0+m)*CSD + kt + ka];
    }
    int cb = t & 63, kb = t >> 6;
#pragma unroll
    for (int p = 0; p < 4; ++p) {
      int kk = kb + p*4;
      Bt[kk*64 + cb] = wcol_val(Wq,Wkv,Wqp,Wkvp, kt+kk, c0+cb);
    }
    __syncthreads();
#pragma unroll
    for (int k = 0; k < 16; ++k) {
      float a0 = At[(rr*4+0)*17 + k];
      float a1 = At[(rr*4+1)*17 + k];
      float a2 = At[(rr*4+2)*17 + k];
      float a3 = At[(rr*4+3)*17 + k];
      float4 b4 = *(const float4*)&Bt[k*64 + cc*4];
      acc[0][0] = fmaf(a0,b4.x,acc[0][0]); acc[0][1] = fmaf(a0,b4.y,acc[0][1]);
      acc[0][2] = fmaf(a0,b4.z,acc[0][2]); acc[0][3] = fmaf(a0,b4.w,acc[0][3]);
      acc[1][0] = fmaf(a1,b4.x,acc[1][0]); acc[1][1] = fmaf(a1,b4.y,acc[1][1]);
      acc[1][2] = fmaf(a1,b4.z,acc[1][2]); acc[1][3] = fmaf(a1,b4.w,acc[1][3]);
      acc[2][0] = fmaf(a2,b4.x,acc[2][0]); acc[2][1] = fmaf(a2,b4.y,acc[2][1]);
      acc[2][2] = fmaf(a2,b4.z,acc[2][2]); acc[2][3] = fmaf(a2,b4.w,acc[2][3]);
      acc[3][0] = fmaf(a3,b4.x,acc[3][0]); acc[3][1] = fmaf(a3,b4.y,acc[3][1]);
      acc[3][2] = fmaf(a3,b4.z,acc[3][2]); acc[3][3] = fmaf(a3,b4.w,acc[3][3]);
    }
    __syncthreads();
  }
  float* qbuf = ws + OFF_Q; float* kbuf = ws + OFF_K; float* vbuf = ws + OFF_V;
  float* raw  = ws + OFF_RAW;
#pragma unroll
  for (int jj = 0; jj < 4; ++jj) {
    int col = c0 + cc*4 + jj;
    float bv = bias_val(bq,bkv,bqp,bkvp,col);
#pragma unroll
    for (int ii = 0; ii < 4; ++ii) {
      int row = r0 + rr*4 + ii;
      float val = acc[ii][jj] + bv;
      if (col < 192) {
        int h = col >> 4, c = col & 15;
        qbuf[(h*NN + row)*CD + c] = val;
      } else if (col < 576) {
        int u = col - 192; int h = u >> 5; int c2 = u & 31;
        if (c2 < 16) kbuf[(h*NN+row)*CD + c2] = val;
        else         vbuf[(h*NN+row)*CD + (c2-16)] = val;
      } else {
        raw[row*576 + (col-576)] = val;
      }
    }
  }
}

// ---------------- K1b: rotate+translate points ----------------
__global__ __launch_bounds__(256) void k_points(const float* __restrict__ rot,
    const float* __restrict__ trans, float* __restrict__ ws) {
  int tg = blockIdx.x*256 + threadIdx.x;      // < 768*192
  int n = tg / 192, pidx = tg % 192;
  const float* raw = ws + OFF_RAW + n*576;
  float v0, v1, v2;
  if (pidx < 48) { v0 = raw[pidx]; v1 = raw[48+pidx]; v2 = raw[96+pidx]; }
  else { int pp = pidx-48; v0 = raw[144+pp]; v1 = raw[288+pp]; v2 = raw[432+pp]; }
  const float* R = rot + n*9; const float* T = trans + n*3;
  float g0 = R[0]*v0 + R[1]*v1 + R[2]*v2 + T[0];
  float g1 = R[3]*v0 + R[4]*v1 + R[5]*v2 + T[1];
  float g2 = R[6]*v0 + R[7]*v1 + R[8]*v2 + T[2];
  if (pidx < 48) {
    int h = pidx >> 2, p = pidx & 3;
    float* qp = ws + OFF_QP + ((h*NN + n)*PQD + p)*3;
    qp[0]=g0; qp[1]=g1; qp[2]=g2;
  } else {
    int pp = pidx - 48; int h = pp/12; int q12 = pp - 12*h;
    if (q12 < 4) { float* kp = ws + OFF_KP + ((h*NN+n)*PQD + q12)*3; kp[0]=g0; kp[1]=g1; kp[2]=g2; }
    else         { float* vp = ws + OFF_VP + ((h*NN+n)*PVD + (q12-4))*3; vp[0]=g0; vp[1]=g1; vp[2]=g2; }
  }
}

// ---------------- K2 v7: bmat = sqrt(1/3)*(z @ W_b + b_b), layout (i,h,j) ----------------
// v6 residual (148us vs 48us HBM floor) was: (a) 96-VGPR weight cache ->
// ~150 VGPR -> 2 waves/SIMD + 1152-block tail round; (b) full 4-level
// butterfly on all 12 accs = 48 bpermute + 48 add per step on the serial
// path. v7: 32 lanes per row (4 c/lane) -> wbr[4][12]=48 VGPR (~95 total,
// 4 waves/SIMD); grid 1024 = exactly 4 blocks/CU; reduce-scatter butterfly
// halves the kept h-set per level via give/keep cndmask exchange: 13 shfl
// per step (vs 48), and final h values land distributed (12 writer lanes x
// 1 float per row). Depth-2 register prefetch (32KB/CU in flight).
__global__ __launch_bounds__(256) void k_bias(const float* __restrict__ z,
    const float* __restrict__ Wb, const float* __restrict__ bb, float* __restrict__ ws) {
  int t = threadIdx.x;
  int q = t & 31;      // c-slice lane within row group
  int rs = t >> 5;     // row slot 0..7
  float wbr[4][12];
#pragma unroll
  for (int cc = 0; cc < 4; ++cc) {
    const float* wp = Wb + (q*4 + cc)*HD;
#pragma unroll
    for (int h = 0; h < 12; ++h) wbr[cc][h] = wp[h];
  }
  const int b4 = (q>>4)&1, b3 = (q>>3)&1, b2 = (q>>2)&1, b1 = (q>>1)&1, b0 = q&1;
  const int hmine = 6*b4 + 3*b3 + (b2 ? 2 : b1);
  const bool writer = (b0 == 0) && (b2 == 0 || b1 == 0);
  const float bbh = bb[hmine];

  const int base = blockIdx.x * 576;         // 1024 blocks x 576 rows = 768*768
  const float* zp = z + (size_t)(base + rs)*CZD + q*4;
  float4 p0 = *(const float4*)(zp);
  float4 p1 = *(const float4*)(zp + 8*CZD);
  float* bmat = ws + OFF_B;
  const float s2 = 0.57735026918962576f;
  for (int s = 0; s < 72; ++s) {
    float4 za = p0; p0 = p1;
    if (s < 70) p1 = *(const float4*)(zp + (size_t)(s+2)*8*CZD);
    float acc[12];
#pragma unroll
    for (int h = 0; h < 12; ++h) {
      float a = za.x * wbr[0][h];
      a = fmaf(za.y, wbr[1][h], a);
      a = fmaf(za.z, wbr[2][h], a);
      a = fmaf(za.w, wbr[3][h], a);
      acc[h] = a;
    }
    // L1: xor 16, 12 -> 6 (keep h = 6*b4 + m)
    float na[6];
#pragma unroll
    for (int m = 0; m < 6; ++m) {
      float keep = b4 ? acc[m+6] : acc[m];
      float give = b4 ? acc[m]   : acc[m+6];
      na[m] = keep + __shfl_xor(give, 16);
    }
    // L2: xor 8, 6 -> 3 (keep h = 6*b4 + 3*b3 + m)
    float nb[3];
#pragma unroll
    for (int m = 0; m < 3; ++m) {
      float keep = b3 ? na[m+3] : na[m];
      float give = b3 ? na[m]   : na[m+3];
      nb[m] = keep + __shfl_xor(give, 8);
    }
    // L3: xor 4, 3 -> 2/1 (b2=0 keeps {+0,+1}; b2=1 keeps {+2})
    float k0 = b2 ? nb[2] : nb[0];
    float g0v = b2 ? nb[0] : nb[2];
    float k1 = b2 ? 0.f   : nb[1];
    float g1v = b2 ? nb[1] : 0.f;
    float c0v = k0 + __shfl_xor(g0v, 4);
    float c1v = k1 + __shfl_xor(g1v, 4);
    // L4: xor 2 (b2=0 splits by b1; b2=1 same-h exchange)
    float k2 = b2 ? c0v : (b1 ? c1v : c0v);
    float g2v = b2 ? c0v : (b1 ? c0v : c1v);
    float d0 = k2 + __shfl_xor(g2v, 2);
    // L5: xor 1 (same-h exchange)
    float e0 = d0 + __shfl_xor(d0, 1);
    if (writer) {
      int r = base + 8*s + rs;
      int i = r / NN;
      int j = r - i*NN;
      bmat[((size_t)i*HD + hmine)*NN + j] = s2*(e0 + bbh);
    }
  }
}

// ---------------- K3: logits + softmax -> a (h,i,j) ----------------
__global__ __launch_bounds__(256) void k_attn(
    const float* __restrict__ mask, const float* __restrict__ ss,
    const float* __restrict__ hwts, float* __restrict__ ws) {
  int h = blockIdx.x, i = blockIdx.y;
  int t = threadIdx.x;
  __shared__ float qsm[16];
  __shared__ float qpsm[12];
  __shared__ float wred[8];
  const float* qbuf = ws + OFF_Q; const float* kbuf = ws + OFF_K;
  const float* qp   = ws + OFF_QP; const float* kp  = ws + OFF_KP;
  const float* bmat = ws + OFF_B;
  float* abuf = ws + OFF_A;
  if (t < 16) qsm[t] = qbuf[(h*NN+i)*CD + t];
  else if (t < 28) qpsm[t-16] = qp[(h*NN+i)*12 + (t-16)];
  __syncthreads();
  float coef = -0.5f * 0.13608276348795434f * log1pf(__expf(hwts[h]));
  float mi = mask[i];
  const float s1 = 0.14433756729740643f;
  float l3[3], ss3[3];
#pragma unroll
  for (int jj = 0; jj < 3; ++jj) {
    int j = t + jj*256;
    const float4* kb = (const float4*)(kbuf + (h*NN+j)*CD);
    float dot = 0.f;
#pragma unroll
    for (int u = 0; u < 4; ++u) {
      float4 kv = kb[u];
      dot = fmaf(qsm[u*4+0], kv.x, dot);
      dot = fmaf(qsm[u*4+1], kv.y, dot);
      dot = fmaf(qsm[u*4+2], kv.z, dot);
      dot = fmaf(qsm[u*4+3], kv.w, dot);
    }
    const float4* kpb = (const float4*)(kp + (h*NN+j)*12);
    float pts = 0.f;
#pragma unroll
    for (int u = 0; u < 3; ++u) {
      float4 kpv = kpb[u];
      float d;
      d = qpsm[u*4+0]-kpv.x; pts = fmaf(d,d,pts);
      d = qpsm[u*4+1]-kpv.y; pts = fmaf(d,d,pts);
      d = qpsm[u*4+2]-kpv.z; pts = fmaf(d,d,pts);
      d = qpsm[u*4+3]-kpv.w; pts = fmaf(d,d,pts);
    }
    float bterm = bmat[((size_t)i*HD + h)*NN + j];
    float lg = fmaf(dot, s1, bterm) + coef*pts + 100000.0f*(mi*mask[j] - 1.0f);
    l3[jj] = lg; ss3[jj] = ss[i*NN + j];
  }
  float mx = fmaxf(l3[0], fmaxf(l3[1], l3[2]));
#pragma unroll
  for (int off = 32; off >= 1; off >>= 1) mx = fmaxf(mx, __shfl_xor(mx, off));
  if ((t & 63) == 0) wred[t>>6] = mx;
  __syncthreads();
  mx = fmaxf(fmaxf(wred[0],wred[1]), fmaxf(wred[2],wred[3]));
  float e3[3]; float sum = 0.f;
#pragma unroll
  for (int jj = 0; jj < 3; ++jj) {
    e3[jj] = __expf(l3[jj]-mx) * (__expf(ss3[jj]) - 0.99f);
    sum += e3[jj];
  }
#pragma unroll
  for (int off = 32; off >= 1; off >>= 1) sum += __shfl_xor(sum, off);
  if ((t & 63) == 0) wred[4 + (t>>6)] = sum;
  __syncthreads();
  sum = (wred[4]+wred[5]) + (wred[6]+wred[7]);
  float inv = 1.0f / sum;
#pragma unroll
  for (int jj = 0; jj < 3; ++jj)
    abuf[((size_t)h*NN + i)*NN + t + jj*256] = e3[jj]*inv;
}

// ---------------- K4: o and o_pt (+norm) -> cat[0:576) ----------------
__global__ __launch_bounds__(256) void k_out_v(
    const float* __restrict__ rot, const float* __restrict__ trans, float* __restrict__ ws) {
  int h = blockIdx.x;
  int i = blockIdx.y*4 + (threadIdx.x >> 6);
  int lane = threadIdx.x & 63;
  const float* abuf = ws + OFF_A; const float* vbuf = ws + OFF_V; const float* vpbuf = ws + OFF_VP;
  float* cat = ws + OFF_CAT;
  const float* arow = abuf + ((size_t)h*NN + i)*NN;
  float acc = 0.f;
  if (lane < 40) {
    const float* ptr; int stride;
    if (lane < 16) { ptr = vbuf + (size_t)(h*NN)*CD + lane; stride = CD; }
    else           { ptr = vpbuf + (size_t)(h*NN)*24 + (lane-16); stride = 24; }
    for (int j = 0; j < NN; j += 4) {
      float4 a4 = *(const float4*)(arow + j);
      float x0 = ptr[0];
      float x1 = ptr[stride];
      float x2 = ptr[2*stride];
      float x3 = ptr[3*stride];
      ptr += 4*stride;
      acc = fmaf(a4.x, x0, acc);
      acc = fmaf(a4.y, x1, acc);
      acc = fmaf(a4.z, x2, acc);
      acc = fmaf(a4.w, x3, acc);
    }
  }
  if (lane < 16) {
    cat[(size_t)i*CATD + h*CD + lane] = acc;
  } else if (lane < 40) {
    int pv = lane - 16; int p = pv/3; int x = pv - 3*p;
    int base = 16 + p*3;
    float g0 = __shfl(acc, base+0);
    float g1 = __shfl(acc, base+1);
    float g2 = __shfl(acc, base+2);
    float v0 = g0 - trans[i*3+0];
    float v1 = g1 - trans[i*3+1];
    float v2 = g2 - trans[i*3+2];
    float loc = rot[i*9 + 0*3 + x]*v0 + rot[i*9 + 1*3 + x]*v1 + rot[i*9 + 2*3 + x]*v2;
    cat[(size_t)i*CATD + 192 + x*96 + h*PVD + p] = loc;
    float sq = loc*loc;
    float n2 = __shfl(sq, base+0) + __shfl(sq, base+1) + __shfl(sq, base+2);
    if (x == 0) cat[(size_t)i*CATD + 480 + h*PVD + p] = sqrtf(n2 + 1e-8f);
  }
}

// ---------------- K5 v2: o_pair = a . z -> cat[576:2112) ----------------
__global__ __launch_bounds__(256) void k_out_pair(const float* __restrict__ z, float* __restrict__ ws) {
  __shared__ float a_sm[HD*NN];        // 36 KB
  __shared__ float4 psm[4][HD][32];    // 24 KB
  int i = blockIdx.x;
  int t = threadIdx.x;
  const float* abuf = ws + OFF_A;
  float* cat = ws + OFF_CAT;
  for (int h = 0; h < HD; ++h) {
    if (t < 192)
      *(float4*)&a_sm[h*NN + t*4] = *(const float4*)(abuf + ((size_t)h*NN + i)*NN + t*4);
  }
  __syncthreads();
  int c4 = t & 31, jc = t >> 5;     // 8 j-slices of 96; wave holds 2 slices
  const float* zbase = z + ((size_t)i*NN + (size_t)jc*96)*CZD + c4*4;
  float4 acc[12];
#pragma unroll
  for (int h = 0; h < 12; ++h) acc[h] = make_float4(0.f,0.f,0.f,0.f);
  for (int jj = 0; jj < 96; jj += 4) {
    float4 z0 = *(const float4*)(zbase + (size_t)(jj+0)*CZD);
    float4 z1 = *(const float4*)(zbase + (size_t)(jj+1)*CZD);
    float4 z2 = *(const float4*)(zbase + (size_t)(jj+2)*CZD);
    float4 z3 = *(const float4*)(zbase + (size_t)(jj+3)*CZD);
    int j0 = jc*96 + jj;
#pragma unroll
    for (int h = 0; h < 12; ++h) {
      float4 av = *(const float4*)&a_sm[h*NN + j0];
      acc[h].x = fmaf(av.x, z0.x, acc[h].x); acc[h].y = fmaf(av.x, z0.y, acc[h].y);
      acc[h].z = fmaf(av.x, z0.z, acc[h].z); acc[h].w = fmaf(av.x, z0.w, acc[h].w);
      acc[h].x = fmaf(av.y, z1.x, acc[h].x); acc[h].y = fmaf(av.y, z1.y, acc[h].y);
      acc[h].z = fmaf(av.y, z1.z, acc[h].z); acc[h].w = fmaf(av.y, z1.w, acc[h].w);
      acc[h].x = fmaf(av.z, z2.x, acc[h].x); acc[h].y = fmaf(av.z, z2.y, acc[h].y);
      acc[h].z = fmaf(av.z, z2.z, acc[h].z); acc[h].w = fmaf(av.z, z2.w, acc[h].w);
      acc[h].x = fmaf(av.w, z3.x, acc[h].x); acc[h].y = fmaf(av.w, z3.y, acc[h].y);
      acc[h].z = fmaf(av.w, z3.z, acc[h].z); acc[h].w = fmaf(av.w, z3.w, acc[h].w);
    }
  }
  int wv = t >> 6, ln = t & 63;
#pragma unroll
  for (int h = 0; h < 12; ++h) {
    acc[h].x += __shfl_down(acc[h].x, 32);
    acc[h].y += __shfl_down(acc[h].y, 32);
    acc[h].z += __shfl_down(acc[h].z, 32);
    acc[h].w += __shfl_down(acc[h].w, 32);
  }
  if (ln < 32) {
#pragma unroll
    for (int h = 0; h < 12; ++h) psm[wv][h][ln] = acc[h];
  }
  __syncthreads();
  for (int o = t; o < 384; o += 256) {
    int h = o >> 5, cc = o & 31;
    float4 s0 = psm[0][h][cc], s1 = psm[1][h][cc], s2 = psm[2][h][cc], s3 = psm[3][h][cc];
    float4 r;
    r.x = (s0.x+s1.x)+(s2.x+s3.x);
    r.y = (s0.y+s1.y)+(s2.y+s3.y);
    r.z = (s0.z+s1.z)+(s2.z+s3.z);
    r.w = (s0.w+s1.w)+(s2.w+s3.w);
    *(float4*)&cat[(size_t)i*CATD + 576 + h*CZD + cc*4] = r;
  }
}

// ---------------- K6: out = cat @ W_out + b_out ----------------
__global__ __launch_bounds__(256) void k_init_out(const float* __restrict__ bout, float* __restrict__ out) {
  int idx = blockIdx.x*256 + threadIdx.x;
  if (idx < NN*CSD) out[idx] = bout[idx % CSD];
}

__global__ __launch_bounds__(256) void k_final(const float* __restrict__ Wout,
    float* __restrict__ out, const float* __restrict__ ws) {
  __shared__ float At[64*17];
  __shared__ float Bt[16*64];
  const float* cat = ws + OFF_CAT;
  int t = threadIdx.x;
  int c0 = blockIdx.x*64, r0 = blockIdx.y*64;
  int kstart = blockIdx.z*528;
  float acc[4][4] = {};
  int cc = t & 15, rr = t >> 4;
  for (int kt = 0; kt < 528; kt += 16) {
    int ka = t & 15, mb = t >> 4;
#pragma unroll
    for (int p = 0; p < 4; ++p) {
      int m = mb + p*16;
      At[m*17 + ka] = cat[(size_t)(r0+m)*CATD + kstart + kt + ka];
    }
    int cb = t & 63, kb = t >> 6;
#pragma unroll
    for (int p = 0; p < 4; ++p) {
      int kk = kb + p*4;
      Bt[kk*64 + cb] = Wout[(size_t)(kstart+kt+kk)*CSD + c0 + cb];
    }
    __syncthreads();
#pragma unroll
    for (int k = 0; k < 16; ++k) {
      float a0 = At[(rr*4+0)*17 + k];
      float a1 = At[(rr*4+1)*17 + k];
      float a2 = At[(rr*4+2)*17 + k];
      float a3 = At[(rr*4+3)*17 + k];
      float4 b4 = *(const float4*)&Bt[k*64 + cc*4];
      acc[0][0] = fmaf(a0,b4.x,acc[0][0]); acc[0][1] = fmaf(a0,b4.y,acc[0][1]);
      acc[0][2] = fmaf(a0,b4.z,acc[0][2]); acc[0][3] = fmaf(a0,b4.w,acc[0][3]);
      acc[1][0] = fmaf(a1,b4.x,acc[1][0]); acc[1][1] = fmaf(a1,b4.y,acc[1][1]);
      acc[1][2] = fmaf(a1,b4.z,acc[1][2]); acc[1][3] = fmaf(a1,b4.w,acc[1][3]);
      acc[2][0] = fmaf(a2,b4.x,acc[2][0]); acc[2][1] = fmaf(a2,b4.y,acc[2][1]);
      acc[2][2] = fmaf(a2,b4.z,acc[2][2]); acc[2][3] = fmaf(a2,b4.w,acc[2][3]);
      acc[3][0] = fmaf(a3,b4.x,acc[3][0]); acc[3][1] = fmaf(a3,b4.y,acc[3][1]);
      acc[3][2] = fmaf(a3,b4.z,acc[3][2]); acc[3][3] = fmaf(a3,b4.w,acc[3][3]);
    }
    __syncthreads();
  }
#pragma unroll
  for (int ii = 0; ii < 4; ++ii)
#pragma unroll
    for (int jj = 0; jj < 4; ++jj)
      atomicAdd(&out[(size_t)(r0+rr*4+ii)*CSD + c0 + cc*4 + jj], acc[ii][jj]);
}

extern "C" void kernel_launch(void* const* d_in, const int* in_sizes, int n_in,
                              void* d_out, int out_size, void* d_ws, size_t ws_size,
                              hipStream_t stream) {
  const float* s    = (const float*)d_in[0];
  const float* z    = (const float*)d_in[1];
  const float* rot  = (const float*)d_in[2];
  const float* trans= (const float*)d_in[3];
  const float* mask = (const float*)d_in[4];
  const float* ss   = (const float*)d_in[5];
  const float* Wq   = (const float*)d_in[6];
  const float* bq   = (const float*)d_in[7];
  const float* Wkv  = (const float*)d_in[8];
  const float* bkv  = (const float*)d_in[9];
  const float* Wqp  = (const float*)d_in[10];
  const float* bqp  = (const float*)d_in[11];
  const float* Wkvp = (const float*)d_in[12];
  const float* bkvp = (const float*)d_in[13];
  const float* Wb   = (const float*)d_in[14];
  const float* bb   = (const float*)d_in[15];
  const float* hw   = (const float*)d_in[16];
  const float* Wout = (const float*)d_in[17];
  const float* bout = (const float*)d_in[18];
  float* ws  = (float*)d_ws;
  float* out = (float*)d_out;

  hipLaunchKernelGGL(k_proj, dim3(18,12), dim3(256), 0, stream,
                     s, Wq,bq, Wkv,bkv, Wqp,bqp, Wkvp,bkvp, ws);
  hipLaunchKernelGGL(k_points, dim3(576), dim3(256), 0, stream, rot, trans, ws);
  hipLaunchKernelGGL(k_bias, dim3(1024), dim3(256), 0, stream, z, Wb, bb, ws);
  hipLaunchKernelGGL(k_attn, dim3(12,768), dim3(256), 0, stream, mask, ss, hw, ws);
  hipLaunchKernelGGL(k_out_v, dim3(12,192), dim3(256), 0, stream, rot, trans, ws);
  hipLaunchKernelGGL(k_out_pair, dim3(768), dim3(256), 0, stream, z, ws);
  hipLaunchKernelGGL(k_init_out, dim3(1152), dim3(256), 0, stream, bout, out);
  hipLaunchKernelGGL(k_final, dim3(6,12,4), dim3(256), 0, stream, Wout, out, ws);
}

// Round 4
// 825.051 us; speedup vs baseline: 1.0979x; 1.0049x over previous
//
#include <hip/hip_runtime.h>
#include <math.h>

#define NN 768
#define CSD 384
#define HD 12
#define CD 16
#define PQD 4
#define PVD 8
#define CZD 128
#define CATD 2112

// ws float offsets
#define OFF_Q      0u
#define OFF_K      147456u
#define OFF_V      294912u
#define OFF_QP     442368u
#define OFF_KP     552960u
#define OFF_VP     663552u
#define OFF_RAW    884736u
#define OFF_B      1327104u
#define OFF_A      8404992u
#define OFF_CAT    15482880u

__device__ __forceinline__ float wcol_val(const float* Wq, const float* Wkv,
                                          const float* Wqp, const float* Wkvp,
                                          int k, int col) {
  if (col < 192) return Wq[k*192 + col];
  if (col < 576) return Wkv[k*384 + (col-192)];
  if (col < 720) return Wqp[k*144 + (col-576)];
  return Wkvp[k*432 + (col-720)];
}
__device__ __forceinline__ float bias_val(const float* bq, const float* bkv,
                                          const float* bqp, const float* bkvp, int col) {
  if (col < 192) return bq[col];
  if (col < 576) return bkv[col-192];
  if (col < 720) return bqp[col-576];
  return bkvp[col-720];
}

// ---------------- K1: s @ [W_q | W_kv | W_qp | W_kvp] + bias ----------------
__global__ __launch_bounds__(256) void k_proj(const float* __restrict__ s,
    const float* __restrict__ Wq, const float* __restrict__ bq,
    const float* __restrict__ Wkv, const float* __restrict__ bkv,
    const float* __restrict__ Wqp, const float* __restrict__ bqp,
    const float* __restrict__ Wkvp, const float* __restrict__ bkvp,
    float* __restrict__ ws) {
  __shared__ float At[64*17];   // [m][k], padded
  __shared__ float Bt[16*64];   // [k][c]
  int t = threadIdx.x;
  int c0 = blockIdx.x * 64;
  int r0 = blockIdx.y * 64;
  float acc[4][4] = {};
  int cc = t & 15, rr = t >> 4;
  for (int kt = 0; kt < CSD; kt += 16) {
    int ka = t & 15, mb = t >> 4;
#pragma unroll
    for (int p = 0; p < 4; ++p) {
      int m = mb + p*16;
      At[m*17 + ka] = s[(r0+m)*CSD + kt + ka];
    }
    int cb = t & 63, kb = t >> 6;
#pragma unroll
    for (int p = 0; p < 4; ++p) {
      int kk = kb + p*4;
      Bt[kk*64 + cb] = wcol_val(Wq,Wkv,Wqp,Wkvp, kt+kk, c0+cb);
    }
    __syncthreads();
#pragma unroll
    for (int k = 0; k < 16; ++k) {
      float a0 = At[(rr*4+0)*17 + k];
      float a1 = At[(rr*4+1)*17 + k];
      float a2 = At[(rr*4+2)*17 + k];
      float a3 = At[(rr*4+3)*17 + k];
      float4 b4 = *(const float4*)&Bt[k*64 + cc*4];
      acc[0][0] = fmaf(a0,b4.x,acc[0][0]); acc[0][1] = fmaf(a0,b4.y,acc[0][1]);
      acc[0][2] = fmaf(a0,b4.z,acc[0][2]); acc[0][3] = fmaf(a0,b4.w,acc[0][3]);
      acc[1][0] = fmaf(a1,b4.x,acc[1][0]); acc[1][1] = fmaf(a1,b4.y,acc[1][1]);
      acc[1][2] = fmaf(a1,b4.z,acc[1][2]); acc[1][3] = fmaf(a1,b4.w,acc[1][3]);
      acc[2][0] = fmaf(a2,b4.x,acc[2][0]); acc[2][1] = fmaf(a2,b4.y,acc[2][1]);
      acc[2][2] = fmaf(a2,b4.z,acc[2][2]); acc[2][3] = fmaf(a2,b4.w,acc[2][3]);
      acc[3][0] = fmaf(a3,b4.x,acc[3][0]); acc[3][1] = fmaf(a3,b4.y,acc[3][1]);
      acc[3][2] = fmaf(a3,b4.z,acc[3][2]); acc[3][3] = fmaf(a3,b4.w,acc[3][3]);
    }
    __syncthreads();
  }
  float* qbuf = ws + OFF_Q; float* kbuf = ws + OFF_K; float* vbuf = ws + OFF_V;
  float* raw  = ws + OFF_RAW;
#pragma unroll
  for (int jj = 0; jj < 4; ++jj) {
    int col = c0 + cc*4 + jj;
    float bv = bias_val(bq,bkv,bqp,bkvp,col);
#pragma unroll
    for (int ii = 0; ii < 4; ++ii) {
      int row = r0 + rr*4 + ii;
      float val = acc[ii][jj] + bv;
      if (col < 192) {
        int h = col >> 4, c = col & 15;
        qbuf[(h*NN + row)*CD + c] = val;
      } else if (col < 576) {
        int u = col - 192; int h = u >> 5; int c2 = u & 31;
        if (c2 < 16) kbuf[(h*NN+row)*CD + c2] = val;
        else         vbuf[(h*NN+row)*CD + (c2-16)] = val;
      } else {
        raw[row*576 + (col-576)] = val;
      }
    }
  }
}

// ---------------- K1b: rotate+translate points (+ init out, fused) ----------------
__global__ __launch_bounds__(256) void k_points(const float* __restrict__ rot,
    const float* __restrict__ trans, const float* __restrict__ bout,
    float* __restrict__ out, float* __restrict__ ws) {
  int bx = blockIdx.x;
  if (bx >= 576) {                       // fused k_init_out: blocks 576..1727
    int idx = (bx - 576)*256 + threadIdx.x;
    out[idx] = bout[idx % CSD];          // 1152*256 == NN*CSD exactly
    return;
  }
  int tg = bx*256 + threadIdx.x;         // < 768*192
  int n = tg / 192, pidx = tg % 192;
  const float* raw = ws + OFF_RAW + n*576;
  float v0, v1, v2;
  if (pidx < 48) { v0 = raw[pidx]; v1 = raw[48+pidx]; v2 = raw[96+pidx]; }
  else { int pp = pidx-48; v0 = raw[144+pp]; v1 = raw[288+pp]; v2 = raw[432+pp]; }
  const float* R = rot + n*9; const float* T = trans + n*3;
  float g0 = R[0]*v0 + R[1]*v1 + R[2]*v2 + T[0];
  float g1 = R[3]*v0 + R[4]*v1 + R[5]*v2 + T[1];
  float g2 = R[6]*v0 + R[7]*v1 + R[8]*v2 + T[2];
  if (pidx < 48) {
    int h = pidx >> 2, p = pidx & 3;
    float* qp = ws + OFF_QP + ((h*NN + n)*PQD + p)*3;
    qp[0]=g0; qp[1]=g1; qp[2]=g2;
  } else {
    int pp = pidx - 48; int h = pp/12; int q12 = pp - 12*h;
    if (q12 < 4) { float* kp = ws + OFF_KP + ((h*NN+n)*PQD + q12)*3; kp[0]=g0; kp[1]=g1; kp[2]=g2; }
    else         { float* vp = ws + OFF_VP + ((h*NN+n)*PVD + (q12-4))*3; vp[0]=g0; vp[1]=g1; vp[2]=g2; }
  }
}

// ---------------- K2 v8: bmat = sqrt(1/3)*(z @ W_b + b_b), layout (i,h,j) ----------------
// v7 (direct-global + 5-level reduce-scatter) plateaued at ~128us (2.4 TB/s):
// the coalescing constraint and the cross-lane reduction were welded together.
// v8 decouples them via LDS staging: stage 128-row tiles (pad 130 floats ->
// conflict-free-ish b64 access both sides), then compute with 16 lanes/row
// (8 c's each, Wb slice in 96 VGPRs -- free, occupancy is LDS-limited at
// 2 blocks/CU), 4-level reduce-scatter (12 shfl per 16-row pass). Budget:
// HBM 48us, VALU ~15us, DS ~19us -> ~55-65us.
#define BR 128
#define BPAD 130
__global__ __launch_bounds__(256) void k_bias(const float* __restrict__ z,
    const float* __restrict__ Wb, const float* __restrict__ bb, float* __restrict__ ws) {
  __shared__ float zt[BR*BPAD];          // 66560 B -> 2 blocks/CU
  int t = threadIdx.x;
  int q = t & 15;                        // c-octet: c in [8q, 8q+8)
  int rg = t >> 4;                       // row slot within pass (0..15)
  float wbr[8][12];
#pragma unroll
  for (int cc = 0; cc < 8; ++cc) {
    const float* wp = Wb + (q*8 + cc)*HD;
#pragma unroll
    for (int h = 0; h < 12; ++h) wbr[cc][h] = wp[h];
  }
  const int b3=(q>>3)&1, b2=(q>>2)&1, b1=(q>>1)&1, b0=q&1;
  const int hmine = 6*b3 + 3*b2 + (b1 ? 2 : b0);
  const bool writer = !(b1 && b0);
  const float bbh = bb[hmine];

  const int rowbase = blockIdx.x * 1152;     // 512 blocks x 9 tiles x 128 rows
  float* bmat = ws + OFF_B;
  const float s2 = 0.57735026918962576f;

  for (int T = 0; T < 9; ++T) {
    int r0 = rowbase + T*BR;
    // ---- stage: 128 rows x 128 floats, global-coalesced ----
#pragma unroll 4
    for (int it = 0; it < 16; ++it) {
      int g = it*256 + t;                  // float4 index in tile
      int row = g >> 5, f4 = g & 31;
      float4 v = *(const float4*)(z + (size_t)(r0+row)*CZD + f4*4);
      float* d = &zt[row*BPAD + f4*4];     // 8B-aligned (pad 130)
      *(float2*)(d)   = make_float2(v.x, v.y);
      *(float2*)(d+2) = make_float2(v.z, v.w);
    }
    __syncthreads();
    // ---- compute: 8 passes x 16 rows ----
#pragma unroll 2
    for (int ps = 0; ps < 8; ++ps) {
      int row = ps*16 + rg;
      const float* zr = &zt[row*BPAD + q*8];
      float2 z01 = *(const float2*)(zr);
      float2 z23 = *(const float2*)(zr+2);
      float2 z45 = *(const float2*)(zr+4);
      float2 z67 = *(const float2*)(zr+6);
      float acc[12];
#pragma unroll
      for (int h = 0; h < 12; ++h) {
        float a = z01.x*wbr[0][h];
        a = fmaf(z01.y, wbr[1][h], a);
        a = fmaf(z23.x, wbr[2][h], a);
        a = fmaf(z23.y, wbr[3][h], a);
        a = fmaf(z45.x, wbr[4][h], a);
        a = fmaf(z45.y, wbr[5][h], a);
        a = fmaf(z67.x, wbr[6][h], a);
        a = fmaf(z67.y, wbr[7][h], a);
        acc[h] = a;
      }
      // L1 xor8: 12 -> 6 (keep h = 6*b3 + m)
      float na[6];
#pragma unroll
      for (int m = 0; m < 6; ++m) {
        float keep = b3 ? acc[m+6] : acc[m];
        float give = b3 ? acc[m]   : acc[m+6];
        na[m] = keep + __shfl_xor(give, 8);
      }
      // L2 xor4: 6 -> 3 (keep h = 6*b3 + 3*b2 + m)
      float nb[3];
#pragma unroll
      for (int m = 0; m < 3; ++m) {
        float keep = b2 ? na[m+3] : na[m];
        float give = b2 ? na[m]   : na[m+3];
        nb[m] = keep + __shfl_xor(give, 4);
      }
      // L3 xor2: b1==0 keeps {m0,m1}; b1==1 keeps {m2}
      float k0 = b1 ? nb[2] : nb[0];
      float g0v = b1 ? nb[0] : nb[2];
      float k1 = b1 ? 0.f   : nb[1];
      float g1v = b1 ? nb[1] : 0.f;
      float c0v = k0 + __shfl_xor(g0v, 2);
      float c1v = k1 + __shfl_xor(g1v, 2);
      // L4 xor1
      float k2 = b1 ? c0v : (b0 ? c1v : c0v);
      float g2v = b1 ? c0v : (b0 ? c0v : c1v);
      float d0 = k2 + __shfl_xor(g2v, 1);
      if (writer) {
        int r = r0 + row;
        int i = r / NN;
        int j = r - i*NN;
        bmat[((size_t)i*HD + hmine)*NN + j] = s2*(d0 + bbh);
      }
    }
    __syncthreads();   // protect zt before next stage
  }
}

// ---------------- K3: logits + softmax -> a (h,i,j) ----------------
__global__ __launch_bounds__(256) void k_attn(
    const float* __restrict__ mask, const float* __restrict__ ss,
    const float* __restrict__ hwts, float* __restrict__ ws) {
  int h = blockIdx.x, i = blockIdx.y;
  int t = threadIdx.x;
  __shared__ float qsm[16];
  __shared__ float qpsm[12];
  __shared__ float wred[8];
  const float* qbuf = ws + OFF_Q; const float* kbuf = ws + OFF_K;
  const float* qp   = ws + OFF_QP; const float* kp  = ws + OFF_KP;
  const float* bmat = ws + OFF_B;
  float* abuf = ws + OFF_A;
  if (t < 16) qsm[t] = qbuf[(h*NN+i)*CD + t];
  else if (t < 28) qpsm[t-16] = qp[(h*NN+i)*12 + (t-16)];
  __syncthreads();
  float coef = -0.5f * 0.13608276348795434f * log1pf(__expf(hwts[h]));
  float mi = mask[i];
  const float s1 = 0.14433756729740643f;
  float l3[3], ss3[3];
#pragma unroll
  for (int jj = 0; jj < 3; ++jj) {
    int j = t + jj*256;
    const float4* kb = (const float4*)(kbuf + (h*NN+j)*CD);
    float dot = 0.f;
#pragma unroll
    for (int u = 0; u < 4; ++u) {
      float4 kv = kb[u];
      dot = fmaf(qsm[u*4+0], kv.x, dot);
      dot = fmaf(qsm[u*4+1], kv.y, dot);
      dot = fmaf(qsm[u*4+2], kv.z, dot);
      dot = fmaf(qsm[u*4+3], kv.w, dot);
    }
    const float4* kpb = (const float4*)(kp + (h*NN+j)*12);
    float pts = 0.f;
#pragma unroll
    for (int u = 0; u < 3; ++u) {
      float4 kpv = kpb[u];
      float d;
      d = qpsm[u*4+0]-kpv.x; pts = fmaf(d,d,pts);
      d = qpsm[u*4+1]-kpv.y; pts = fmaf(d,d,pts);
      d = qpsm[u*4+2]-kpv.z; pts = fmaf(d,d,pts);
      d = qpsm[u*4+3]-kpv.w; pts = fmaf(d,d,pts);
    }
    float bterm = bmat[((size_t)i*HD + h)*NN + j];
    float lg = fmaf(dot, s1, bterm) + coef*pts + 100000.0f*(mi*mask[j] - 1.0f);
    l3[jj] = lg; ss3[jj] = ss[i*NN + j];
  }
  float mx = fmaxf(l3[0], fmaxf(l3[1], l3[2]));
#pragma unroll
  for (int off = 32; off >= 1; off >>= 1) mx = fmaxf(mx, __shfl_xor(mx, off));
  if ((t & 63) == 0) wred[t>>6] = mx;
  __syncthreads();
  mx = fmaxf(fmaxf(wred[0],wred[1]), fmaxf(wred[2],wred[3]));
  float e3[3]; float sum = 0.f;
#pragma unroll
  for (int jj = 0; jj < 3; ++jj) {
    e3[jj] = __expf(l3[jj]-mx) * (__expf(ss3[jj]) - 0.99f);
    sum += e3[jj];
  }
#pragma unroll
  for (int off = 32; off >= 1; off >>= 1) sum += __shfl_xor(sum, off);
  if ((t & 63) == 0) wred[4 + (t>>6)] = sum;
  __syncthreads();
  sum = (wred[4]+wred[5]) + (wred[6]+wred[7]);
  float inv = 1.0f / sum;
#pragma unroll
  for (int jj = 0; jj < 3; ++jj)
    abuf[((size_t)h*NN + i)*NN + t + jj*256] = e3[jj]*inv;
}

// ---------------- K4: o and o_pt (+norm) -> cat[0:576) ----------------
__global__ __launch_bounds__(256) void k_out_v(
    const float* __restrict__ rot, const float* __restrict__ trans, float* __restrict__ ws) {
  int h = blockIdx.x;
  int i = blockIdx.y*4 + (threadIdx.x >> 6);
  int lane = threadIdx.x & 63;
  const float* abuf = ws + OFF_A; const float* vbuf = ws + OFF_V; const float* vpbuf = ws + OFF_VP;
  float* cat = ws + OFF_CAT;
  const float* arow = abuf + ((size_t)h*NN + i)*NN;
  float acc = 0.f;
  if (lane < 40) {
    const float* ptr; int stride;
    if (lane < 16) { ptr = vbuf + (size_t)(h*NN)*CD + lane; stride = CD; }
    else           { ptr = vpbuf + (size_t)(h*NN)*24 + (lane-16); stride = 24; }
    for (int j = 0; j < NN; j += 4) {
      float4 a4 = *(const float4*)(arow + j);
      float x0 = ptr[0];
      float x1 = ptr[stride];
      float x2 = ptr[2*stride];
      float x3 = ptr[3*stride];
      ptr += 4*stride;
      acc = fmaf(a4.x, x0, acc);
      acc = fmaf(a4.y, x1, acc);
      acc = fmaf(a4.z, x2, acc);
      acc = fmaf(a4.w, x3, acc);
    }
  }
  if (lane < 16) {
    cat[(size_t)i*CATD + h*CD + lane] = acc;
  } else if (lane < 40) {
    int pv = lane - 16; int p = pv/3; int x = pv - 3*p;
    int base = 16 + p*3;
    float g0 = __shfl(acc, base+0);
    float g1 = __shfl(acc, base+1);
    float g2 = __shfl(acc, base+2);
    float v0 = g0 - trans[i*3+0];
    float v1 = g1 - trans[i*3+1];
    float v2 = g2 - trans[i*3+2];
    float loc = rot[i*9 + 0*3 + x]*v0 + rot[i*9 + 1*3 + x]*v1 + rot[i*9 + 2*3 + x]*v2;
    cat[(size_t)i*CATD + 192 + x*96 + h*PVD + p] = loc;
    float sq = loc*loc;
    float n2 = __shfl(sq, base+0) + __shfl(sq, base+1) + __shfl(sq, base+2);
    if (x == 0) cat[(size_t)i*CATD + 480 + h*PVD + p] = sqrtf(n2 + 1e-8f);
  }
}

// ---------------- K5 v3: o_pair = a . z -> cat[576:2112) ----------------
// v2 used 60KB LDS -> 2 blocks/CU -> 768 blocks ran in 1.5 rounds (half the
// machine idle in round 2). v3: psm shrunk to 2 wave-slots via two-stage
// cross-wave reduction (+1 barrier) -> 48KB -> 3 blocks/CU -> one round.
__global__ __launch_bounds__(256) void k_out_pair(const float* __restrict__ z, float* __restrict__ ws) {
  __shared__ float a_sm[HD*NN];        // 36 KB
  __shared__ float4 psm[2][HD][32];    // 12 KB
  int i = blockIdx.x;
  int t = threadIdx.x;
  const float* abuf = ws + OFF_A;
  float* cat = ws + OFF_CAT;
  for (int h = 0; h < HD; ++h) {
    if (t < 192)
      *(float4*)&a_sm[h*NN + t*4] = *(const float4*)(abuf + ((size_t)h*NN + i)*NN + t*4);
  }
  __syncthreads();
  int c4 = t & 31, jc = t >> 5;     // 8 j-slices of 96; wave holds 2 slices
  const float* zbase = z + ((size_t)i*NN + (size_t)jc*96)*CZD + c4*4;
  float4 acc[12];
#pragma unroll
  for (int h = 0; h < 12; ++h) acc[h] = make_float4(0.f,0.f,0.f,0.f);
  for (int jj = 0; jj < 96; jj += 4) {
    float4 z0 = *(const float4*)(zbase + (size_t)(jj+0)*CZD);
    float4 z1 = *(const float4*)(zbase + (size_t)(jj+1)*CZD);
    float4 z2 = *(const float4*)(zbase + (size_t)(jj+2)*CZD);
    float4 z3 = *(const float4*)(zbase + (size_t)(jj+3)*CZD);
    int j0 = jc*96 + jj;
#pragma unroll
    for (int h = 0; h < 12; ++h) {
      float4 av = *(const float4*)&a_sm[h*NN + j0];
      acc[h].x = fmaf(av.x, z0.x, acc[h].x); acc[h].y = fmaf(av.x, z0.y, acc[h].y);
      acc[h].z = fmaf(av.x, z0.z, acc[h].z); acc[h].w = fmaf(av.x, z0.w, acc[h].w);
      acc[h].x = fmaf(av.y, z1.x, acc[h].x); acc[h].y = fmaf(av.y, z1.y, acc[h].y);
      acc[h].z = fmaf(av.y, z1.z, acc[h].z); acc[h].w = fmaf(av.y, z1.w, acc[h].w);
      acc[h].x = fmaf(av.z, z2.x, acc[h].x); acc[h].y = fmaf(av.z, z2.y, acc[h].y);
      acc[h].z = fmaf(av.z, z2.z, acc[h].z); acc[h].w = fmaf(av.z, z2.w, acc[h].w);
      acc[h].x = fmaf(av.w, z3.x, acc[h].x); acc[h].y = fmaf(av.w, z3.y, acc[h].y);
      acc[h].z = fmaf(av.w, z3.z, acc[h].z); acc[h].w = fmaf(av.w, z3.w, acc[h].w);
    }
  }
  int wv = t >> 6, ln = t & 63;
#pragma unroll
  for (int h = 0; h < 12; ++h) {
    acc[h].x += __shfl_down(acc[h].x, 32);
    acc[h].y += __shfl_down(acc[h].y, 32);
    acc[h].z += __shfl_down(acc[h].z, 32);
    acc[h].w += __shfl_down(acc[h].w, 32);
  }
  if (wv >= 2 && ln < 32) {
#pragma unroll
    for (int h = 0; h < 12; ++h) psm[wv-2][h][ln] = acc[h];
  }
  __syncthreads();
  if (wv < 2 && ln < 32) {
#pragma unroll
    for (int h = 0; h < 12; ++h) {
      float4 p = psm[wv][h][ln];
      acc[h].x += p.x; acc[h].y += p.y; acc[h].z += p.z; acc[h].w += p.w;
      psm[wv][h][ln] = acc[h];
    }
  }
  __syncthreads();
  for (int o = t; o < 384; o += 256) {
    int h = o >> 5, cc = o & 31;
    float4 s0 = psm[0][h][cc], s1 = psm[1][h][cc];
    float4 r;
    r.x = s0.x + s1.x;
    r.y = s0.y + s1.y;
    r.z = s0.z + s1.z;
    r.w = s0.w + s1.w;
    *(float4*)&cat[(size_t)i*CATD + 576 + h*CZD + cc*4] = r;
  }
}

// ---------------- K6: out = cat @ W_out + b_out ----------------
__global__ __launch_bounds__(256) void k_final(const float* __restrict__ Wout,
    float* __restrict__ out, const float* __restrict__ ws) {
  __shared__ float At[64*17];
  __shared__ float Bt[16*64];
  const float* cat = ws + OFF_CAT;
  int t = threadIdx.x;
  int c0 = blockIdx.x*64, r0 = blockIdx.y*64;
  int kstart = blockIdx.z*528;
  float acc[4][4] = {};
  int cc = t & 15, rr = t >> 4;
  for (int kt = 0; kt < 528; kt += 16) {
    int ka = t & 15, mb = t >> 4;
#pragma unroll
    for (int p = 0; p < 4; ++p) {
      int m = mb + p*16;
      At[m*17 + ka] = cat[(size_t)(r0+m)*CATD + kstart + kt + ka];
    }
    int cb = t & 63, kb = t >> 6;
#pragma unroll
    for (int p = 0; p < 4; ++p) {
      int kk = kb + p*4;
      Bt[kk*64 + cb] = Wout[(size_t)(kstart+kt+kk)*CSD + c0 + cb];
    }
    __syncthreads();
#pragma unroll
    for (int k = 0; k < 16; ++k) {
      float a0 = At[(rr*4+0)*17 + k];
      float a1 = At[(rr*4+1)*17 + k];
      float a2 = At[(rr*4+2)*17 + k];
      float a3 = At[(rr*4+3)*17 + k];
      float4 b4 = *(const float4*)&Bt[k*64 + cc*4];
      acc[0][0] = fmaf(a0,b4.x,acc[0][0]); acc[0][1] = fmaf(a0,b4.y,acc[0][1]);
      acc[0][2] = fmaf(a0,b4.z,acc[0][2]); acc[0][3] = fmaf(a0,b4.w,acc[0][3]);
      acc[1][0] = fmaf(a1,b4.x,acc[1][0]); acc[1][1] = fmaf(a1,b4.y,acc[1][1]);
      acc[1][2] = fmaf(a1,b4.z,acc[1][2]); acc[1][3] = fmaf(a1,b4.w,acc[1][3]);
      acc[2][0] = fmaf(a2,b4.x,acc[2][0]); acc[2][1] = fmaf(a2,b4.y,acc[2][1]);
      acc[2][2] = fmaf(a2,b4.z,acc[2][2]); acc[2][3] = fmaf(a2,b4.w,acc[2][3]);
      acc[3][0] = fmaf(a3,b4.x,acc[3][0]); acc[3][1] = fmaf(a3,b4.y,acc[3][1]);
      acc[3][2] = fmaf(a3,b4.z,acc[3][2]); acc[3][3] = fmaf(a3,b4.w,acc[3][3]);
    }
    __syncthreads();
  }
#pragma unroll
  for (int ii = 0; ii < 4; ++ii)
#pragma unroll
    for (int jj = 0; jj < 4; ++jj)
      atomicAdd(&out[(size_t)(r0+rr*4+ii)*CSD + c0 + cc*4 + jj], acc[ii][jj]);
}

extern "C" void kernel_launch(void* const* d_in, const int* in_sizes, int n_in,
                              void* d_out, int out_size, void* d_ws, size_t ws_size,
                              hipStream_t stream) {
  const float* s    = (const float*)d_in[0];
  const float* z    = (const float*)d_in[1];
  const float* rot  = (const float*)d_in[2];
  const float* trans= (const float*)d_in[3];
  const float* mask = (const float*)d_in[4];
  const float* ss   = (const float*)d_in[5];
  const float* Wq   = (const float*)d_in[6];
  const float* bq   = (const float*)d_in[7];
  const float* Wkv  = (const float*)d_in[8];
  const float* bkv  = (const float*)d_in[9];
  const float* Wqp  = (const float*)d_in[10];
  const float* bqp  = (const float*)d_in[11];
  const float* Wkvp = (const float*)d_in[12];
  const float* bkvp = (const float*)d_in[13];
  const float* Wb   = (const float*)d_in[14];
  const float* bb   = (const float*)d_in[15];
  const float* hw   = (const float*)d_in[16];
  const float* Wout = (const float*)d_in[17];
  const float* bout = (const float*)d_in[18];
  float* ws  = (float*)d_ws;
  float* out = (float*)d_out;

  hipLaunchKernelGGL(k_proj, dim3(18,12), dim3(256), 0, stream,
                     s, Wq,bq, Wkv,bkv, Wqp,bqp, Wkvp,bkvp, ws);
  hipLaunchKernelGGL(k_points, dim3(1728), dim3(256), 0, stream, rot, trans, bout, out, ws);
  hipLaunchKernelGGL(k_bias, dim3(512), dim3(256), 0, stream, z, Wb, bb, ws);
  hipLaunchKernelGGL(k_attn, dim3(12,768), dim3(256), 0, stream, mask, ss, hw, ws);
  hipLaunchKernelGGL(k_out_v, dim3(12,192), dim3(256), 0, stream, rot, trans, ws);
  hipLaunchKernelGGL(k_out_pair, dim3(768), dim3(256), 0, stream, z, ws);
  hipLaunchKernelGGL(k_final, dim3(6,12,4), dim3(256), 0, stream, Wout, out, ws);
}

// Round 5
// 737.655 us; speedup vs baseline: 1.2279x; 1.1185x over previous
//
#include <hip/hip_runtime.h>
#include <math.h>

#define NN 768
#define CSD 384
#define HD 12
#define CD 16
#define PQD 4
#define PVD 8
#define CZD 128
#define CATD 2112

// ws float offsets
#define OFF_Q      0u
#define OFF_K      147456u
#define OFF_V      294912u
#define OFF_QP     442368u
#define OFF_KP     552960u
#define OFF_VP     663552u
#define OFF_RAW    884736u
#define OFF_B      1327104u
#define OFF_A      8404992u
#define OFF_CAT    15482880u

__device__ __forceinline__ float wcol_val(const float* Wq, const float* Wkv,
                                          const float* Wqp, const float* Wkvp,
                                          int k, int col) {
  if (col < 192) return Wq[k*192 + col];
  if (col < 576) return Wkv[k*384 + (col-192)];
  if (col < 720) return Wqp[k*144 + (col-576)];
  return Wkvp[k*432 + (col-720)];
}
__device__ __forceinline__ float bias_val(const float* bq, const float* bkv,
                                          const float* bqp, const float* bkvp, int col) {
  if (col < 192) return bq[col];
  if (col < 576) return bkv[col-192];
  if (col < 720) return bqp[col-576];
  return bkvp[col-720];
}

// ---------------- K1: s @ [W_q | W_kv | W_qp | W_kvp] + bias ----------------
__global__ __launch_bounds__(256) void k_proj(const float* __restrict__ s,
    const float* __restrict__ Wq, const float* __restrict__ bq,
    const float* __restrict__ Wkv, const float* __restrict__ bkv,
    const float* __restrict__ Wqp, const float* __restrict__ bqp,
    const float* __restrict__ Wkvp, const float* __restrict__ bkvp,
    float* __restrict__ ws) {
  __shared__ float At[64*17];   // [m][k], padded
  __shared__ float Bt[16*64];   // [k][c]
  int t = threadIdx.x;
  int c0 = blockIdx.x * 64;
  int r0 = blockIdx.y * 64;
  float acc[4][4] = {};
  int cc = t & 15, rr = t >> 4;
  for (int kt = 0; kt < CSD; kt += 16) {
    int ka = t & 15, mb = t >> 4;
#pragma unroll
    for (int p = 0; p < 4; ++p) {
      int m = mb + p*16;
      At[m*17 + ka] = s[(r0+m)*CSD + kt + ka];
    }
    int cb = t & 63, kb = t >> 6;
#pragma unroll
    for (int p = 0; p < 4; ++p) {
      int kk = kb + p*4;
      Bt[kk*64 + cb] = wcol_val(Wq,Wkv,Wqp,Wkvp, kt+kk, c0+cb);
    }
    __syncthreads();
#pragma unroll
    for (int k = 0; k < 16; ++k) {
      float a0 = At[(rr*4+0)*17 + k];
      float a1 = At[(rr*4+1)*17 + k];
      float a2 = At[(rr*4+2)*17 + k];
      float a3 = At[(rr*4+3)*17 + k];
      float4 b4 = *(const float4*)&Bt[k*64 + cc*4];
      acc[0][0] = fmaf(a0,b4.x,acc[0][0]); acc[0][1] = fmaf(a0,b4.y,acc[0][1]);
      acc[0][2] = fmaf(a0,b4.z,acc[0][2]); acc[0][3] = fmaf(a0,b4.w,acc[0][3]);
      acc[1][0] = fmaf(a1,b4.x,acc[1][0]); acc[1][1] = fmaf(a1,b4.y,acc[1][1]);
      acc[1][2] = fmaf(a1,b4.z,acc[1][2]); acc[1][3] = fmaf(a1,b4.w,acc[1][3]);
      acc[2][0] = fmaf(a2,b4.x,acc[2][0]); acc[2][1] = fmaf(a2,b4.y,acc[2][1]);
      acc[2][2] = fmaf(a2,b4.z,acc[2][2]); acc[2][3] = fmaf(a2,b4.w,acc[2][3]);
      acc[3][0] = fmaf(a3,b4.x,acc[3][0]); acc[3][1] = fmaf(a3,b4.y,acc[3][1]);
      acc[3][2] = fmaf(a3,b4.z,acc[3][2]); acc[3][3] = fmaf(a3,b4.w,acc[3][3]);
    }
    __syncthreads();
  }
  float* qbuf = ws + OFF_Q; float* kbuf = ws + OFF_K; float* vbuf = ws + OFF_V;
  float* raw  = ws + OFF_RAW;
#pragma unroll
  for (int jj = 0; jj < 4; ++jj) {
    int col = c0 + cc*4 + jj;
    float bv = bias_val(bq,bkv,bqp,bkvp,col);
#pragma unroll
    for (int ii = 0; ii < 4; ++ii) {
      int row = r0 + rr*4 + ii;
      float val = acc[ii][jj] + bv;
      if (col < 192) {
        int h = col >> 4, c = col & 15;
        qbuf[(h*NN + row)*CD + c] = val;
      } else if (col < 576) {
        int u = col - 192; int h = u >> 5; int c2 = u & 31;
        if (c2 < 16) kbuf[(h*NN+row)*CD + c2] = val;
        else         vbuf[(h*NN+row)*CD + (c2-16)] = val;
      } else {
        raw[row*576 + (col-576)] = val;
      }
    }
  }
}

// ---------------- K1b: rotate+translate points (+ init out, fused) ----------------
__global__ __launch_bounds__(256) void k_points(const float* __restrict__ rot,
    const float* __restrict__ trans, const float* __restrict__ bout,
    float* __restrict__ out, float* __restrict__ ws) {
  int bx = blockIdx.x;
  if (bx >= 576) {                       // fused k_init_out: blocks 576..1727
    int idx = (bx - 576)*256 + threadIdx.x;
    out[idx] = bout[idx % CSD];          // 1152*256 == NN*CSD exactly
    return;
  }
  int tg = bx*256 + threadIdx.x;         // < 768*192
  int n = tg / 192, pidx = tg % 192;
  const float* raw = ws + OFF_RAW + n*576;
  float v0, v1, v2;
  if (pidx < 48) { v0 = raw[pidx]; v1 = raw[48+pidx]; v2 = raw[96+pidx]; }
  else { int pp = pidx-48; v0 = raw[144+pp]; v1 = raw[288+pp]; v2 = raw[432+pp]; }
  const float* R = rot + n*9; const float* T = trans + n*3;
  float g0 = R[0]*v0 + R[1]*v1 + R[2]*v2 + T[0];
  float g1 = R[3]*v0 + R[4]*v1 + R[5]*v2 + T[1];
  float g2 = R[6]*v0 + R[7]*v1 + R[8]*v2 + T[2];
  if (pidx < 48) {
    int h = pidx >> 2, p = pidx & 3;
    float* qp = ws + OFF_QP + ((h*NN + n)*PQD + p)*3;
    qp[0]=g0; qp[1]=g1; qp[2]=g2;
  } else {
    int pp = pidx - 48; int h = pp/12; int q12 = pp - 12*h;
    if (q12 < 4) { float* kp = ws + OFF_KP + ((h*NN+n)*PQD + q12)*3; kp[0]=g0; kp[1]=g1; kp[2]=g2; }
    else         { float* vp = ws + OFF_VP + ((h*NN+n)*PVD + (q12-4))*3; vp[0]=g0; vp[1]=g1; vp[2]=g2; }
  }
}

// ---------------- K2 v8: bmat = sqrt(1/3)*(z @ W_b + b_b), layout (i,h,j) ----------------
#define BR 128
#define BPAD 130
__global__ __launch_bounds__(256) void k_bias(const float* __restrict__ z,
    const float* __restrict__ Wb, const float* __restrict__ bb, float* __restrict__ ws) {
  __shared__ float zt[BR*BPAD];          // 66560 B -> 2 blocks/CU
  int t = threadIdx.x;
  int q = t & 15;                        // c-octet: c in [8q, 8q+8)
  int rg = t >> 4;                       // row slot within pass (0..15)
  float wbr[8][12];
#pragma unroll
  for (int cc = 0; cc < 8; ++cc) {
    const float* wp = Wb + (q*8 + cc)*HD;
#pragma unroll
    for (int h = 0; h < 12; ++h) wbr[cc][h] = wp[h];
  }
  const int b3=(q>>3)&1, b2=(q>>2)&1, b1=(q>>1)&1, b0=q&1;
  const int hmine = 6*b3 + 3*b2 + (b1 ? 2 : b0);
  const bool writer = !(b1 && b0);
  const float bbh = bb[hmine];

  const int rowbase = blockIdx.x * 1152;     // 512 blocks x 9 tiles x 128 rows
  float* bmat = ws + OFF_B;
  const float s2 = 0.57735026918962576f;

  for (int T = 0; T < 9; ++T) {
    int r0 = rowbase + T*BR;
#pragma unroll 4
    for (int it = 0; it < 16; ++it) {
      int g = it*256 + t;                  // float4 index in tile
      int row = g >> 5, f4 = g & 31;
      float4 v = *(const float4*)(z + (size_t)(r0+row)*CZD + f4*4);
      float* d = &zt[row*BPAD + f4*4];     // 8B-aligned (pad 130)
      *(float2*)(d)   = make_float2(v.x, v.y);
      *(float2*)(d+2) = make_float2(v.z, v.w);
    }
    __syncthreads();
#pragma unroll 2
    for (int ps = 0; ps < 8; ++ps) {
      int row = ps*16 + rg;
      const float* zr = &zt[row*BPAD + q*8];
      float2 z01 = *(const float2*)(zr);
      float2 z23 = *(const float2*)(zr+2);
      float2 z45 = *(const float2*)(zr+4);
      float2 z67 = *(const float2*)(zr+6);
      float acc[12];
#pragma unroll
      for (int h = 0; h < 12; ++h) {
        float a = z01.x*wbr[0][h];
        a = fmaf(z01.y, wbr[1][h], a);
        a = fmaf(z23.x, wbr[2][h], a);
        a = fmaf(z23.y, wbr[3][h], a);
        a = fmaf(z45.x, wbr[4][h], a);
        a = fmaf(z45.y, wbr[5][h], a);
        a = fmaf(z67.x, wbr[6][h], a);
        a = fmaf(z67.y, wbr[7][h], a);
        acc[h] = a;
      }
      float na[6];
#pragma unroll
      for (int m = 0; m < 6; ++m) {
        float keep = b3 ? acc[m+6] : acc[m];
        float give = b3 ? acc[m]   : acc[m+6];
        na[m] = keep + __shfl_xor(give, 8);
      }
      float nb[3];
#pragma unroll
      for (int m = 0; m < 3; ++m) {
        float keep = b2 ? na[m+3] : na[m];
        float give = b2 ? na[m]   : na[m+3];
        nb[m] = keep + __shfl_xor(give, 4);
      }
      float k0 = b1 ? nb[2] : nb[0];
      float g0v = b1 ? nb[0] : nb[2];
      float k1 = b1 ? 0.f   : nb[1];
      float g1v = b1 ? nb[1] : 0.f;
      float c0v = k0 + __shfl_xor(g0v, 2);
      float c1v = k1 + __shfl_xor(g1v, 2);
      float k2 = b1 ? c0v : (b0 ? c1v : c0v);
      float g2v = b1 ? c0v : (b0 ? c0v : c1v);
      float d0 = k2 + __shfl_xor(g2v, 1);
      if (writer) {
        int r = r0 + row;
        int i = r / NN;
        int j = r - i*NN;
        bmat[((size_t)i*HD + hmine)*NN + j] = s2*(d0 + bbh);
      }
    }
    __syncthreads();   // protect zt before next stage
  }
}

// ---------------- K3 fused: softmax (all h) + o/o_pt + o_pair, one block per i ----------------
// Replaces k_attn + k_out_v + k_out_pair. a never touches HBM (was 28MB W +
// 56MB R): phase A computes all 12 heads' softmax rows into a_sm (LDS),
// phase B consumes it for o/o_pt (LDS broadcast reads), phase C streams z
// for o_pair. LDS 48KB -> 3 blocks/CU, 768 blocks = one round.
__global__ __launch_bounds__(256) void k_fused(
    const float* __restrict__ z,
    const float* __restrict__ rot, const float* __restrict__ trans,
    const float* __restrict__ mask, const float* __restrict__ ss,
    const float* __restrict__ hwts, float* __restrict__ ws) {
  __shared__ float a_sm[HD*NN];        // 36 KB
  __shared__ float4 psm[2][HD][32];    // 12 KB
  __shared__ float wred[8];
  int i = blockIdx.x;
  int t = threadIdx.x;
  const float* qbuf = ws + OFF_Q; const float* kbuf = ws + OFF_K;
  const float* qp   = ws + OFF_QP; const float* kp  = ws + OFF_KP;
  const float* vbuf = ws + OFF_V;  const float* vpbuf = ws + OFF_VP;
  const float* bmat = ws + OFF_B;
  float* cat = ws + OFF_CAT;
  const float s1 = 0.14433756729740643f;

  // hoisted per-thread, h-invariant terms
  float mi = mask[i];
  float msk3[3], ss3[3];
#pragma unroll
  for (int jj = 0; jj < 3; ++jj) {
    int j = t + jj*256;
    msk3[jj] = 100000.0f*(mi*mask[j] - 1.0f);
    ss3[jj]  = __expf(ss[i*NN + j]) - 0.99f;
  }

  // ---- phase A: logits + softmax for all 12 h -> a_sm ----
  for (int h = 0; h < HD; ++h) {
    const float4* qv4 = (const float4*)(qbuf + (h*NN+i)*CD);
    float4 q0 = qv4[0], q1 = qv4[1], q2 = qv4[2], q3 = qv4[3];
    const float4* qp4 = (const float4*)(qp + (h*NN+i)*12);
    float4 p0 = qp4[0], p1 = qp4[1], p2 = qp4[2];
    float coef = -0.5f * 0.13608276348795434f * log1pf(__expf(hwts[h]));
    float l3[3];
#pragma unroll
    for (int jj = 0; jj < 3; ++jj) {
      int j = t + jj*256;
      const float4* kb = (const float4*)(kbuf + (h*NN+j)*CD);
      float dot = 0.f;
      float4 kv;
      kv = kb[0];
      dot = fmaf(q0.x, kv.x, dot); dot = fmaf(q0.y, kv.y, dot);
      dot = fmaf(q0.z, kv.z, dot); dot = fmaf(q0.w, kv.w, dot);
      kv = kb[1];
      dot = fmaf(q1.x, kv.x, dot); dot = fmaf(q1.y, kv.y, dot);
      dot = fmaf(q1.z, kv.z, dot); dot = fmaf(q1.w, kv.w, dot);
      kv = kb[2];
      dot = fmaf(q2.x, kv.x, dot); dot = fmaf(q2.y, kv.y, dot);
      dot = fmaf(q2.z, kv.z, dot); dot = fmaf(q2.w, kv.w, dot);
      kv = kb[3];
      dot = fmaf(q3.x, kv.x, dot); dot = fmaf(q3.y, kv.y, dot);
      dot = fmaf(q3.z, kv.z, dot); dot = fmaf(q3.w, kv.w, dot);
      const float4* kpb = (const float4*)(kp + (h*NN+j)*12);
      float pts = 0.f; float d;
      float4 kpv;
      kpv = kpb[0];
      d = p0.x-kpv.x; pts = fmaf(d,d,pts);
      d = p0.y-kpv.y; pts = fmaf(d,d,pts);
      d = p0.z-kpv.z; pts = fmaf(d,d,pts);
      d = p0.w-kpv.w; pts = fmaf(d,d,pts);
      kpv = kpb[1];
      d = p1.x-kpv.x; pts = fmaf(d,d,pts);
      d = p1.y-kpv.y; pts = fmaf(d,d,pts);
      d = p1.z-kpv.z; pts = fmaf(d,d,pts);
      d = p1.w-kpv.w; pts = fmaf(d,d,pts);
      kpv = kpb[2];
      d = p2.x-kpv.x; pts = fmaf(d,d,pts);
      d = p2.y-kpv.y; pts = fmaf(d,d,pts);
      d = p2.z-kpv.z; pts = fmaf(d,d,pts);
      d = p2.w-kpv.w; pts = fmaf(d,d,pts);
      float bterm = bmat[((size_t)i*HD + h)*NN + j];
      l3[jj] = fmaf(dot, s1, bterm) + coef*pts + msk3[jj];
    }
    float mx = fmaxf(l3[0], fmaxf(l3[1], l3[2]));
#pragma unroll
    for (int off = 32; off >= 1; off >>= 1) mx = fmaxf(mx, __shfl_xor(mx, off));
    if ((t & 63) == 0) wred[t>>6] = mx;
    __syncthreads();
    mx = fmaxf(fmaxf(wred[0],wred[1]), fmaxf(wred[2],wred[3]));
    float e3[3]; float sum = 0.f;
#pragma unroll
    for (int jj = 0; jj < 3; ++jj) {
      e3[jj] = __expf(l3[jj]-mx) * ss3[jj];
      sum += e3[jj];
    }
#pragma unroll
    for (int off = 32; off >= 1; off >>= 1) sum += __shfl_xor(sum, off);
    if ((t & 63) == 0) wred[4 + (t>>6)] = sum;
    __syncthreads();
    sum = (wred[4]+wred[5]) + (wred[6]+wred[7]);
    float inv = 1.0f / sum;
#pragma unroll
    for (int jj = 0; jj < 3; ++jj)
      a_sm[h*NN + t + jj*256] = e3[jj]*inv;
  }
  __syncthreads();

  // ---- phase B: o and o_pt (+norm) -> cat[0:576), wave handles 3 h ----
  int wv = t >> 6, lane = t & 63;
  for (int hh = 0; hh < 3; ++hh) {
    int h = wv*3 + hh;
    float acc = 0.f;
    if (lane < 40) {
      const float* ptr; int stride;
      if (lane < 16) { ptr = vbuf + (size_t)(h*NN)*CD + lane; stride = CD; }
      else           { ptr = vpbuf + (size_t)(h*NN)*24 + (lane-16); stride = 24; }
      const float* arow = &a_sm[h*NN];
      for (int j = 0; j < NN; j += 4) {
        float4 a4 = *(const float4*)(arow + j);
        float x0 = ptr[0];
        float x1 = ptr[stride];
        float x2 = ptr[2*stride];
        float x3 = ptr[3*stride];
        ptr += 4*stride;
        acc = fmaf(a4.x, x0, acc);
        acc = fmaf(a4.y, x1, acc);
        acc = fmaf(a4.z, x2, acc);
        acc = fmaf(a4.w, x3, acc);
      }
    }
    if (lane < 16) {
      cat[(size_t)i*CATD + h*CD + lane] = acc;
    } else if (lane < 40) {
      int pv = lane - 16; int p = pv/3; int x = pv - 3*p;
      int base = 16 + p*3;
      float g0 = __shfl(acc, base+0);
      float g1 = __shfl(acc, base+1);
      float g2 = __shfl(acc, base+2);
      float v0 = g0 - trans[i*3+0];
      float v1 = g1 - trans[i*3+1];
      float v2 = g2 - trans[i*3+2];
      float loc = rot[i*9 + 0*3 + x]*v0 + rot[i*9 + 1*3 + x]*v1 + rot[i*9 + 2*3 + x]*v2;
      cat[(size_t)i*CATD + 192 + x*96 + h*PVD + p] = loc;
      float sq = loc*loc;
      float n2 = __shfl(sq, base+0) + __shfl(sq, base+1) + __shfl(sq, base+2);
      if (x == 0) cat[(size_t)i*CATD + 480 + h*PVD + p] = sqrtf(n2 + 1e-8f);
    }
  }

  // ---- phase C: o_pair = a . z -> cat[576:2112) ----
  int c4 = t & 31, jc = t >> 5;     // 8 j-slices of 96
  const float* zbase = z + ((size_t)i*NN + (size_t)jc*96)*CZD + c4*4;
  float4 acc[12];
#pragma unroll
  for (int h = 0; h < 12; ++h) acc[h] = make_float4(0.f,0.f,0.f,0.f);
  for (int jj = 0; jj < 96; jj += 4) {
    float4 z0 = *(const float4*)(zbase + (size_t)(jj+0)*CZD);
    float4 z1 = *(const float4*)(zbase + (size_t)(jj+1)*CZD);
    float4 z2 = *(const float4*)(zbase + (size_t)(jj+2)*CZD);
    float4 z3 = *(const float4*)(zbase + (size_t)(jj+3)*CZD);
    int j0 = jc*96 + jj;
#pragma unroll
    for (int h = 0; h < 12; ++h) {
      float4 av = *(const float4*)&a_sm[h*NN + j0];
      acc[h].x = fmaf(av.x, z0.x, acc[h].x); acc[h].y = fmaf(av.x, z0.y, acc[h].y);
      acc[h].z = fmaf(av.x, z0.z, acc[h].z); acc[h].w = fmaf(av.x, z0.w, acc[h].w);
      acc[h].x = fmaf(av.y, z1.x, acc[h].x); acc[h].y = fmaf(av.y, z1.y, acc[h].y);
      acc[h].z = fmaf(av.y, z1.z, acc[h].z); acc[h].w = fmaf(av.y, z1.w, acc[h].w);
      acc[h].x = fmaf(av.z, z2.x, acc[h].x); acc[h].y = fmaf(av.z, z2.y, acc[h].y);
      acc[h].z = fmaf(av.z, z2.z, acc[h].z); acc[h].w = fmaf(av.z, z2.w, acc[h].w);
      acc[h].x = fmaf(av.w, z3.x, acc[h].x); acc[h].y = fmaf(av.w, z3.y, acc[h].y);
      acc[h].z = fmaf(av.w, z3.z, acc[h].z); acc[h].w = fmaf(av.w, z3.w, acc[h].w);
    }
  }
  int ln = t & 63;
#pragma unroll
  for (int h = 0; h < 12; ++h) {
    acc[h].x += __shfl_down(acc[h].x, 32);
    acc[h].y += __shfl_down(acc[h].y, 32);
    acc[h].z += __shfl_down(acc[h].z, 32);
    acc[h].w += __shfl_down(acc[h].w, 32);
  }
  if (wv >= 2 && ln < 32) {
#pragma unroll
    for (int h = 0; h < 12; ++h) psm[wv-2][h][ln] = acc[h];
  }
  __syncthreads();
  if (wv < 2 && ln < 32) {
#pragma unroll
    for (int h = 0; h < 12; ++h) {
      float4 p = psm[wv][h][ln];
      acc[h].x += p.x; acc[h].y += p.y; acc[h].z += p.z; acc[h].w += p.w;
      psm[wv][h][ln] = acc[h];
    }
  }
  __syncthreads();
  for (int o = t; o < 384; o += 256) {
    int h = o >> 5, cc = o & 31;
    float4 s0 = psm[0][h][cc], s1 = psm[1][h][cc];
    float4 r;
    r.x = s0.x + s1.x;
    r.y = s0.y + s1.y;
    r.z = s0.z + s1.z;
    r.w = s0.w + s1.w;
    *(float4*)&cat[(size_t)i*CATD + 576 + h*CZD + cc*4] = r;
  }
}

// ---------------- K6: out = cat @ W_out + b_out ----------------
__global__ __launch_bounds__(256) void k_final(const float* __restrict__ Wout,
    float* __restrict__ out, const float* __restrict__ ws) {
  __shared__ float At[64*17];
  __shared__ float Bt[16*64];
  const float* cat = ws + OFF_CAT;
  int t = threadIdx.x;
  int c0 = blockIdx.x*64, r0 = blockIdx.y*64;
  int kstart = blockIdx.z*528;
  float acc[4][4] = {};
  int cc = t & 15, rr = t >> 4;
  for (int kt = 0; kt < 528; kt += 16) {
    int ka = t & 15, mb = t >> 4;
#pragma unroll
    for (int p = 0; p < 4; ++p) {
      int m = mb + p*16;
      At[m*17 + ka] = cat[(size_t)(r0+m)*CATD + kstart + kt + ka];
    }
    int cb = t & 63, kb = t >> 6;
#pragma unroll
    for (int p = 0; p < 4; ++p) {
      int kk = kb + p*4;
      Bt[kk*64 + cb] = Wout[(size_t)(kstart+kt+kk)*CSD + c0 + cb];
    }
    __syncthreads();
#pragma unroll
    for (int k = 0; k < 16; ++k) {
      float a0 = At[(rr*4+0)*17 + k];
      float a1 = At[(rr*4+1)*17 + k];
      float a2 = At[(rr*4+2)*17 + k];
      float a3 = At[(rr*4+3)*17 + k];
      float4 b4 = *(const float4*)&Bt[k*64 + cc*4];
      acc[0][0] = fmaf(a0,b4.x,acc[0][0]); acc[0][1] = fmaf(a0,b4.y,acc[0][1]);
      acc[0][2] = fmaf(a0,b4.z,acc[0][2]); acc[0][3] = fmaf(a0,b4.w,acc[0][3]);
      acc[1][0] = fmaf(a1,b4.x,acc[1][0]); acc[1][1] = fmaf(a1,b4.y,acc[1][1]);
      acc[1][2] = fmaf(a1,b4.z,acc[1][2]); acc[1][3] = fmaf(a1,b4.w,acc[1][3]);
      acc[2][0] = fmaf(a2,b4.x,acc[2][0]); acc[2][1] = fmaf(a2,b4.y,acc[2][1]);
      acc[2][2] = fmaf(a2,b4.z,acc[2][2]); acc[2][3] = fmaf(a2,b4.w,acc[2][3]);
      acc[3][0] = fmaf(a3,b4.x,acc[3][0]); acc[3][1] = fmaf(a3,b4.y,acc[3][1]);
      acc[3][2] = fmaf(a3,b4.z,acc[3][2]); acc[3][3] = fmaf(a3,b4.w,acc[3][3]);
    }
    __syncthreads();
  }
#pragma unroll
  for (int ii = 0; ii < 4; ++ii)
#pragma unroll
    for (int jj = 0; jj < 4; ++jj)
      atomicAdd(&out[(size_t)(r0+rr*4+ii)*CSD + c0 + cc*4 + jj], acc[ii][jj]);
}

extern "C" void kernel_launch(void* const* d_in, const int* in_sizes, int n_in,
                              void* d_out, int out_size, void* d_ws, size_t ws_size,
                              hipStream_t stream) {
  const float* s    = (const float*)d_in[0];
  const float* z    = (const float*)d_in[1];
  const float* rot  = (const float*)d_in[2];
  const float* trans= (const float*)d_in[3];
  const float* mask = (const float*)d_in[4];
  const float* ss   = (const float*)d_in[5];
  const float* Wq   = (const float*)d_in[6];
  const float* bq   = (const float*)d_in[7];
  const float* Wkv  = (const float*)d_in[8];
  const float* bkv  = (const float*)d_in[9];
  const float* Wqp  = (const float*)d_in[10];
  const float* bqp  = (const float*)d_in[11];
  const float* Wkvp = (const float*)d_in[12];
  const float* bkvp = (const float*)d_in[13];
  const float* Wb   = (const float*)d_in[14];
  const float* bb   = (const float*)d_in[15];
  const float* hw   = (const float*)d_in[16];
  const float* Wout = (const float*)d_in[17];
  const float* bout = (const float*)d_in[18];
  float* ws  = (float*)d_ws;
  float* out = (float*)d_out;

  hipLaunchKernelGGL(k_proj, dim3(18,12), dim3(256), 0, stream,
                     s, Wq,bq, Wkv,bkv, Wqp,bqp, Wkvp,bkvp, ws);
  hipLaunchKernelGGL(k_points, dim3(1728), dim3(256), 0, stream, rot, trans, bout, out, ws);
  hipLaunchKernelGGL(k_bias, dim3(512), dim3(256), 0, stream, z, Wb, bb, ws);
  hipLaunchKernelGGL(k_fused, dim3(768), dim3(256), 0, stream, z, rot, trans, mask, ss, hw, ws);
  hipLaunchKernelGGL(k_final, dim3(6,12,4), dim3(256), 0, stream, Wout, out, ws);
}

// Round 6
// 735.611 us; speedup vs baseline: 1.2313x; 1.0028x over previous
//
#include <hip/hip_runtime.h>
#include <math.h>

#define NN 768
#define CSD 384
#define HD 12
#define CD 16
#define PQD 4
#define PVD 8
#define CZD 128
#define CATD 2112

// ws float offsets
#define OFF_Q      0u
#define OFF_K      147456u
#define OFF_V      294912u
#define OFF_QP     442368u
#define OFF_KP     552960u
#define OFF_VP     663552u
#define OFF_RAW    884736u
#define OFF_B      1327104u
#define OFF_A      8404992u
#define OFF_CAT    15482880u

__device__ __forceinline__ float wcol_val(const float* Wq, const float* Wkv,
                                          const float* Wqp, const float* Wkvp,
                                          int k, int col) {
  if (col < 192) return Wq[k*192 + col];
  if (col < 576) return Wkv[k*384 + (col-192)];
  if (col < 720) return Wqp[k*144 + (col-576)];
  return Wkvp[k*432 + (col-720)];
}
__device__ __forceinline__ float bias_val(const float* bq, const float* bkv,
                                          const float* bqp, const float* bkvp, int col) {
  if (col < 192) return bq[col];
  if (col < 576) return bkv[col-192];
  if (col < 720) return bqp[col-576];
  return bkvp[col-720];
}

// ---------------- K1: s @ [W_q | W_kv | W_qp | W_kvp] + bias ----------------
__global__ __launch_bounds__(256) void k_proj(const float* __restrict__ s,
    const float* __restrict__ Wq, const float* __restrict__ bq,
    const float* __restrict__ Wkv, const float* __restrict__ bkv,
    const float* __restrict__ Wqp, const float* __restrict__ bqp,
    const float* __restrict__ Wkvp, const float* __restrict__ bkvp,
    float* __restrict__ ws) {
  __shared__ float At[64*17];   // [m][k], padded
  __shared__ float Bt[16*64];   // [k][c]
  int t = threadIdx.x;
  int c0 = blockIdx.x * 64;
  int r0 = blockIdx.y * 64;
  float acc[4][4] = {};
  int cc = t & 15, rr = t >> 4;
  for (int kt = 0; kt < CSD; kt += 16) {
    int ka = t & 15, mb = t >> 4;
#pragma unroll
    for (int p = 0; p < 4; ++p) {
      int m = mb + p*16;
      At[m*17 + ka] = s[(r0+m)*CSD + kt + ka];
    }
    int cb = t & 63, kb = t >> 6;
#pragma unroll
    for (int p = 0; p < 4; ++p) {
      int kk = kb + p*4;
      Bt[kk*64 + cb] = wcol_val(Wq,Wkv,Wqp,Wkvp, kt+kk, c0+cb);
    }
    __syncthreads();
#pragma unroll
    for (int k = 0; k < 16; ++k) {
      float a0 = At[(rr*4+0)*17 + k];
      float a1 = At[(rr*4+1)*17 + k];
      float a2 = At[(rr*4+2)*17 + k];
      float a3 = At[(rr*4+3)*17 + k];
      float4 b4 = *(const float4*)&Bt[k*64 + cc*4];
      acc[0][0] = fmaf(a0,b4.x,acc[0][0]); acc[0][1] = fmaf(a0,b4.y,acc[0][1]);
      acc[0][2] = fmaf(a0,b4.z,acc[0][2]); acc[0][3] = fmaf(a0,b4.w,acc[0][3]);
      acc[1][0] = fmaf(a1,b4.x,acc[1][0]); acc[1][1] = fmaf(a1,b4.y,acc[1][1]);
      acc[1][2] = fmaf(a1,b4.z,acc[1][2]); acc[1][3] = fmaf(a1,b4.w,acc[1][3]);
      acc[2][0] = fmaf(a2,b4.x,acc[2][0]); acc[2][1] = fmaf(a2,b4.y,acc[2][1]);
      acc[2][2] = fmaf(a2,b4.z,acc[2][2]); acc[2][3] = fmaf(a2,b4.w,acc[2][3]);
      acc[3][0] = fmaf(a3,b4.x,acc[3][0]); acc[3][1] = fmaf(a3,b4.y,acc[3][1]);
      acc[3][2] = fmaf(a3,b4.z,acc[3][2]); acc[3][3] = fmaf(a3,b4.w,acc[3][3]);
    }
    __syncthreads();
  }
  float* qbuf = ws + OFF_Q; float* kbuf = ws + OFF_K; float* vbuf = ws + OFF_V;
  float* raw  = ws + OFF_RAW;
#pragma unroll
  for (int jj = 0; jj < 4; ++jj) {
    int col = c0 + cc*4 + jj;
    float bv = bias_val(bq,bkv,bqp,bkvp,col);
#pragma unroll
    for (int ii = 0; ii < 4; ++ii) {
      int row = r0 + rr*4 + ii;
      float val = acc[ii][jj] + bv;
      if (col < 192) {
        int h = col >> 4, c = col & 15;
        qbuf[(h*NN + row)*CD + c] = val;
      } else if (col < 576) {
        int u = col - 192; int h = u >> 5; int c2 = u & 31;
        if (c2 < 16) kbuf[(h*NN+row)*CD + c2] = val;
        else         vbuf[(h*NN+row)*CD + (c2-16)] = val;
      } else {
        raw[row*576 + (col-576)] = val;
      }
    }
  }
}

// ---------------- K1b: rotate+translate points (+ init out, fused) ----------------
__global__ __launch_bounds__(256) void k_points(const float* __restrict__ rot,
    const float* __restrict__ trans, const float* __restrict__ bout,
    float* __restrict__ out, float* __restrict__ ws) {
  int bx = blockIdx.x;
  if (bx >= 576) {                       // fused k_init_out: blocks 576..1727
    int idx = (bx - 576)*256 + threadIdx.x;
    out[idx] = bout[idx % CSD];          // 1152*256 == NN*CSD exactly
    return;
  }
  int tg = bx*256 + threadIdx.x;         // < 768*192
  int n = tg / 192, pidx = tg % 192;
  const float* raw = ws + OFF_RAW + n*576;
  float v0, v1, v2;
  if (pidx < 48) { v0 = raw[pidx]; v1 = raw[48+pidx]; v2 = raw[96+pidx]; }
  else { int pp = pidx-48; v0 = raw[144+pp]; v1 = raw[288+pp]; v2 = raw[432+pp]; }
  const float* R = rot + n*9; const float* T = trans + n*3;
  float g0 = R[0]*v0 + R[1]*v1 + R[2]*v2 + T[0];
  float g1 = R[3]*v0 + R[4]*v1 + R[5]*v2 + T[1];
  float g2 = R[6]*v0 + R[7]*v1 + R[8]*v2 + T[2];
  if (pidx < 48) {
    int h = pidx >> 2, p = pidx & 3;
    float* qp = ws + OFF_QP + ((h*NN + n)*PQD + p)*3;
    qp[0]=g0; qp[1]=g1; qp[2]=g2;
  } else {
    int pp = pidx - 48; int h = pp/12; int q12 = pp - 12*h;
    if (q12 < 4) { float* kp = ws + OFF_KP + ((h*NN+n)*PQD + q12)*3; kp[0]=g0; kp[1]=g1; kp[2]=g2; }
    else         { float* vp = ws + OFF_VP + ((h*NN+n)*PVD + (q12-4))*3; vp[0]=g0; vp[1]=g1; vp[2]=g2; }
  }
}

// ---------------- K2 v9: bmat = sqrt(1/3)*(z @ W_b + b_b), layout (i,h,j) ----------------
// v8 (single-buffer LDS) was serialized: stage -> barrier -> compute -> barrier,
// no loads in flight during compute => time = stage + compute (~125us).
// v9: double-buffered 48-row tiles (2x48x130x4 = 49.9KB -> 3 blocks/CU; grid
// 768 = exactly 3/CU, one i per block). Per tile: barrier -> ISSUE loads(T+1)
// into regs -> compute(T) -> reg->LDS write(T+1). Compiler's vmcnt wait lands
// before the ds_write (after compute), so HBM latency hides under compute
// (T14 issue-early/write-late). Compute = v7's proven 32-lane 5-level
// reduce-scatter (wbr[4][12]=48 VGPR).
#define BR2 48
#define BPAD 130
__global__ __launch_bounds__(256) void k_bias(const float* __restrict__ z,
    const float* __restrict__ Wb, const float* __restrict__ bb, float* __restrict__ ws) {
  __shared__ float zt[2][BR2*BPAD];      // 49920 B
  int t = threadIdx.x;
  int q = t & 31;                        // c-quad lane: c in [4q, 4q+4)
  int rs = t >> 5;                       // row slot 0..7
  float wbr[4][12];
#pragma unroll
  for (int cc = 0; cc < 4; ++cc) {
    const float* wp = Wb + (q*4 + cc)*HD;
#pragma unroll
    for (int h = 0; h < 12; ++h) wbr[cc][h] = wp[h];
  }
  const int b4=(q>>4)&1, b3=(q>>3)&1, b2=(q>>2)&1, b1=(q>>1)&1, b0=q&1;
  const int hmine = 6*b4 + 3*b3 + (b2 ? 2 : b1);
  const bool writer = (b0 == 0) && (b2 == 0 || b1 == 0);
  const float bbh = bb[hmine];

  const int i = blockIdx.x;              // 768 blocks, one i each (16 tiles x 48 j)
  const float* zi = z + (size_t)i*NN*CZD;
  float* bmat = ws + OFF_B + (size_t)i*HD*NN;
  const float s2 = 0.57735026918962576f;

  float4 st[6];
  // prologue: stage tile 0
#pragma unroll
  for (int it = 0; it < 6; ++it) {
    int g = it*256 + t; int row = g >> 5, f4 = g & 31;
    st[it] = *(const float4*)(zi + (size_t)row*CZD + f4*4);
  }
#pragma unroll
  for (int it = 0; it < 6; ++it) {
    int g = it*256 + t; int row = g >> 5, f4 = g & 31;
    float* d = &zt[0][row*BPAD + f4*4];
    *(float2*)(d)   = make_float2(st[it].x, st[it].y);
    *(float2*)(d+2) = make_float2(st[it].z, st[it].w);
  }
  for (int T = 0; T < 16; ++T) {
    const float* buf = zt[T & 1];
    float* nbuf = zt[(T & 1) ^ 1];
    __syncthreads();                      // zt[T&1] writes visible to all
    if (T < 15) {
      const float* zn = zi + (size_t)(T+1)*BR2*CZD;
#pragma unroll
      for (int it = 0; it < 6; ++it) {    // issue-early: loads fly during compute
        int g = it*256 + t; int row = g >> 5, f4 = g & 31;
        st[it] = *(const float4*)(zn + (size_t)row*CZD + f4*4);
      }
    }
    int j0 = T*BR2;
#pragma unroll
    for (int ps = 0; ps < 6; ++ps) {
      int row = ps*8 + rs;
      const float* zr = &buf[row*BPAD + q*4];
      float2 z01 = *(const float2*)(zr);
      float2 z23 = *(const float2*)(zr+2);
      float acc[12];
#pragma unroll
      for (int h = 0; h < 12; ++h) {
        float a = z01.x*wbr[0][h];
        a = fmaf(z01.y, wbr[1][h], a);
        a = fmaf(z23.x, wbr[2][h], a);
        a = fmaf(z23.y, wbr[3][h], a);
        acc[h] = a;
      }
      // L1 xor16: 12 -> 6
      float na[6];
#pragma unroll
      for (int m = 0; m < 6; ++m) {
        float keep = b4 ? acc[m+6] : acc[m];
        float give = b4 ? acc[m]   : acc[m+6];
        na[m] = keep + __shfl_xor(give, 16);
      }
      // L2 xor8: 6 -> 3
      float nb[3];
#pragma unroll
      for (int m = 0; m < 3; ++m) {
        float keep = b3 ? na[m+3] : na[m];
        float give = b3 ? na[m]   : na[m+3];
        nb[m] = keep + __shfl_xor(give, 8);
      }
      // L3 xor4: b2=0 keeps {m0,m1}; b2=1 keeps {m2}
      float k0 = b2 ? nb[2] : nb[0];
      float g0v = b2 ? nb[0] : nb[2];
      float k1 = b2 ? 0.f   : nb[1];
      float g1v = b2 ? nb[1] : 0.f;
      float c0v = k0 + __shfl_xor(g0v, 4);
      float c1v = k1 + __shfl_xor(g1v, 4);
      // L4 xor2
      float k2 = b2 ? c0v : (b1 ? c1v : c0v);
      float g2v = b2 ? c0v : (b1 ? c0v : c1v);
      float d0 = k2 + __shfl_xor(g2v, 2);
      // L5 xor1
      float e0 = d0 + __shfl_xor(d0, 1);
      if (writer) {
        int j = j0 + row;
        bmat[(size_t)hmine*NN + j] = s2*(e0 + bbh);
      }
    }
    if (T < 15) {                         // write-late: vmcnt waited here, after compute
#pragma unroll
      for (int it = 0; it < 6; ++it) {
        int g = it*256 + t; int row = g >> 5, f4 = g & 31;
        float* d = &nbuf[row*BPAD + f4*4];
        *(float2*)(d)   = make_float2(st[it].x, st[it].y);
        *(float2*)(d+2) = make_float2(st[it].z, st[it].w);
      }
    }
  }
}

// ---------------- K3 fused: softmax (all h) + o/o_pt + o_pair, one block per i ----------------
__global__ __launch_bounds__(256) void k_fused(
    const float* __restrict__ z,
    const float* __restrict__ rot, const float* __restrict__ trans,
    const float* __restrict__ mask, const float* __restrict__ ss,
    const float* __restrict__ hwts, float* __restrict__ ws) {
  __shared__ float a_sm[HD*NN];        // 36 KB
  __shared__ float4 psm[2][HD][32];    // 12 KB
  __shared__ float wred[8];
  int i = blockIdx.x;
  int t = threadIdx.x;
  const float* qbuf = ws + OFF_Q; const float* kbuf = ws + OFF_K;
  const float* qp   = ws + OFF_QP; const float* kp  = ws + OFF_KP;
  const float* vbuf = ws + OFF_V;  const float* vpbuf = ws + OFF_VP;
  const float* bmat = ws + OFF_B;
  float* cat = ws + OFF_CAT;
  const float s1 = 0.14433756729740643f;

  // hoisted per-thread, h-invariant terms
  float mi = mask[i];
  float msk3[3], ss3[3];
#pragma unroll
  for (int jj = 0; jj < 3; ++jj) {
    int j = t + jj*256;
    msk3[jj] = 100000.0f*(mi*mask[j] - 1.0f);
    ss3[jj]  = __expf(ss[i*NN + j]) - 0.99f;
  }

  // ---- phase A: logits + softmax for all 12 h -> a_sm ----
  for (int h = 0; h < HD; ++h) {
    const float4* qv4 = (const float4*)(qbuf + (h*NN+i)*CD);
    float4 q0 = qv4[0], q1 = qv4[1], q2 = qv4[2], q3 = qv4[3];
    const float4* qp4 = (const float4*)(qp + (h*NN+i)*12);
    float4 p0 = qp4[0], p1 = qp4[1], p2 = qp4[2];
    float coef = -0.5f * 0.13608276348795434f * log1pf(__expf(hwts[h]));
    float l3[3];
#pragma unroll
    for (int jj = 0; jj < 3; ++jj) {
      int j = t + jj*256;
      const float4* kb = (const float4*)(kbuf + (h*NN+j)*CD);
      float dot = 0.f;
      float4 kv;
      kv = kb[0];
      dot = fmaf(q0.x, kv.x, dot); dot = fmaf(q0.y, kv.y, dot);
      dot = fmaf(q0.z, kv.z, dot); dot = fmaf(q0.w, kv.w, dot);
      kv = kb[1];
      dot = fmaf(q1.x, kv.x, dot); dot = fmaf(q1.y, kv.y, dot);
      dot = fmaf(q1.z, kv.z, dot); dot = fmaf(q1.w, kv.w, dot);
      kv = kb[2];
      dot = fmaf(q2.x, kv.x, dot); dot = fmaf(q2.y, kv.y, dot);
      dot = fmaf(q2.z, kv.z, dot); dot = fmaf(q2.w, kv.w, dot);
      kv = kb[3];
      dot = fmaf(q3.x, kv.x, dot); dot = fmaf(q3.y, kv.y, dot);
      dot = fmaf(q3.z, kv.z, dot); dot = fmaf(q3.w, kv.w, dot);
      const float4* kpb = (const float4*)(kp + (h*NN+j)*12);
      float pts = 0.f; float d;
      float4 kpv;
      kpv = kpb[0];
      d = p0.x-kpv.x; pts = fmaf(d,d,pts);
      d = p0.y-kpv.y; pts = fmaf(d,d,pts);
      d = p0.z-kpv.z; pts = fmaf(d,d,pts);
      d = p0.w-kpv.w; pts = fmaf(d,d,pts);
      kpv = kpb[1];
      d = p1.x-kpv.x; pts = fmaf(d,d,pts);
      d = p1.y-kpv.y; pts = fmaf(d,d,pts);
      d = p1.z-kpv.z; pts = fmaf(d,d,pts);
      d = p1.w-kpv.w; pts = fmaf(d,d,pts);
      kpv = kpb[2];
      d = p2.x-kpv.x; pts = fmaf(d,d,pts);
      d = p2.y-kpv.y; pts = fmaf(d,d,pts);
      d = p2.z-kpv.z; pts = fmaf(d,d,pts);
      d = p2.w-kpv.w; pts = fmaf(d,d,pts);
      float bterm = bmat[((size_t)i*HD + h)*NN + j];
      l3[jj] = fmaf(dot, s1, bterm) + coef*pts + msk3[jj];
    }
    float mx = fmaxf(l3[0], fmaxf(l3[1], l3[2]));
#pragma unroll
    for (int off = 32; off >= 1; off >>= 1) mx = fmaxf(mx, __shfl_xor(mx, off));
    if ((t & 63) == 0) wred[t>>6] = mx;
    __syncthreads();
    mx = fmaxf(fmaxf(wred[0],wred[1]), fmaxf(wred[2],wred[3]));
    float e3[3]; float sum = 0.f;
#pragma unroll
    for (int jj = 0; jj < 3; ++jj) {
      e3[jj] = __expf(l3[jj]-mx) * ss3[jj];
      sum += e3[jj];
    }
#pragma unroll
    for (int off = 32; off >= 1; off >>= 1) sum += __shfl_xor(sum, off);
    if ((t & 63) == 0) wred[4 + (t>>6)] = sum;
    __syncthreads();
    sum = (wred[4]+wred[5]) + (wred[6]+wred[7]);
    float inv = 1.0f / sum;
#pragma unroll
    for (int jj = 0; jj < 3; ++jj)
      a_sm[h*NN + t + jj*256] = e3[jj]*inv;
  }
  __syncthreads();

  // ---- phase B: o and o_pt (+norm) -> cat[0:576), wave handles 3 h ----
  int wv = t >> 6, lane = t & 63;
  for (int hh = 0; hh < 3; ++hh) {
    int h = wv*3 + hh;
    float acc = 0.f;
    if (lane < 40) {
      const float* ptr; int stride;
      if (lane < 16) { ptr = vbuf + (size_t)(h*NN)*CD + lane; stride = CD; }
      else           { ptr = vpbuf + (size_t)(h*NN)*24 + (lane-16); stride = 24; }
      const float* arow = &a_sm[h*NN];
      for (int j = 0; j < NN; j += 4) {
        float4 a4 = *(const float4*)(arow + j);
        float x0 = ptr[0];
        float x1 = ptr[stride];
        float x2 = ptr[2*stride];
        float x3 = ptr[3*stride];
        ptr += 4*stride;
        acc = fmaf(a4.x, x0, acc);
        acc = fmaf(a4.y, x1, acc);
        acc = fmaf(a4.z, x2, acc);
        acc = fmaf(a4.w, x3, acc);
      }
    }
    if (lane < 16) {
      cat[(size_t)i*CATD + h*CD + lane] = acc;
    } else if (lane < 40) {
      int pv = lane - 16; int p = pv/3; int x = pv - 3*p;
      int base = 16 + p*3;
      float g0 = __shfl(acc, base+0);
      float g1 = __shfl(acc, base+1);
      float g2 = __shfl(acc, base+2);
      float v0 = g0 - trans[i*3+0];
      float v1 = g1 - trans[i*3+1];
      float v2 = g2 - trans[i*3+2];
      float loc = rot[i*9 + 0*3 + x]*v0 + rot[i*9 + 1*3 + x]*v1 + rot[i*9 + 2*3 + x]*v2;
      cat[(size_t)i*CATD + 192 + x*96 + h*PVD + p] = loc;
      float sq = loc*loc;
      float n2 = __shfl(sq, base+0) + __shfl(sq, base+1) + __shfl(sq, base+2);
      if (x == 0) cat[(size_t)i*CATD + 480 + h*PVD + p] = sqrtf(n2 + 1e-8f);
    }
  }

  // ---- phase C: o_pair = a . z -> cat[576:2112), depth-1 z prefetch ----
  int c4 = t & 31, jc = t >> 5;     // 8 j-slices of 96
  const float* zbase = z + ((size_t)i*NN + (size_t)jc*96)*CZD + c4*4;
  float4 acc[12];
#pragma unroll
  for (int h = 0; h < 12; ++h) acc[h] = make_float4(0.f,0.f,0.f,0.f);
  float4 zn0 = *(const float4*)(zbase);
  float4 zn1 = *(const float4*)(zbase + (size_t)1*CZD);
  float4 zn2 = *(const float4*)(zbase + (size_t)2*CZD);
  float4 zn3 = *(const float4*)(zbase + (size_t)3*CZD);
  for (int jj = 0; jj < 96; jj += 4) {
    float4 z0 = zn0, z1 = zn1, z2 = zn2, z3 = zn3;
    if (jj < 92) {
      zn0 = *(const float4*)(zbase + (size_t)(jj+4)*CZD);
      zn1 = *(const float4*)(zbase + (size_t)(jj+5)*CZD);
      zn2 = *(const float4*)(zbase + (size_t)(jj+6)*CZD);
      zn3 = *(const float4*)(zbase + (size_t)(jj+7)*CZD);
    }
    int j0 = jc*96 + jj;
#pragma unroll
    for (int h = 0; h < 12; ++h) {
      float4 av = *(const float4*)&a_sm[h*NN + j0];
      acc[h].x = fmaf(av.x, z0.x, acc[h].x); acc[h].y = fmaf(av.x, z0.y, acc[h].y);
      acc[h].z = fmaf(av.x, z0.z, acc[h].z); acc[h].w = fmaf(av.x, z0.w, acc[h].w);
      acc[h].x = fmaf(av.y, z1.x, acc[h].x); acc[h].y = fmaf(av.y, z1.y, acc[h].y);
      acc[h].z = fmaf(av.y, z1.z, acc[h].z); acc[h].w = fmaf(av.y, z1.w, acc[h].w);
      acc[h].x = fmaf(av.z, z2.x, acc[h].x); acc[h].y = fmaf(av.z, z2.y, acc[h].y);
      acc[h].z = fmaf(av.z, z2.z, acc[h].z); acc[h].w = fmaf(av.z, z2.w, acc[h].w);
      acc[h].x = fmaf(av.w, z3.x, acc[h].x); acc[h].y = fmaf(av.w, z3.y, acc[h].y);
      acc[h].z = fmaf(av.w, z3.z, acc[h].z); acc[h].w = fmaf(av.w, z3.w, acc[h].w);
    }
  }
  int ln = t & 63;
#pragma unroll
  for (int h = 0; h < 12; ++h) {
    acc[h].x += __shfl_down(acc[h].x, 32);
    acc[h].y += __shfl_down(acc[h].y, 32);
    acc[h].z += __shfl_down(acc[h].z, 32);
    acc[h].w += __shfl_down(acc[h].w, 32);
  }
  if (wv >= 2 && ln < 32) {
#pragma unroll
    for (int h = 0; h < 12; ++h) psm[wv-2][h][ln] = acc[h];
  }
  __syncthreads();
  if (wv < 2 && ln < 32) {
#pragma unroll
    for (int h = 0; h < 12; ++h) {
      float4 p = psm[wv][h][ln];
      acc[h].x += p.x; acc[h].y += p.y; acc[h].z += p.z; acc[h].w += p.w;
      psm[wv][h][ln] = acc[h];
    }
  }
  __syncthreads();
  for (int o = t; o < 384; o += 256) {
    int h = o >> 5, cc = o & 31;
    float4 s0 = psm[0][h][cc], s1 = psm[1][h][cc];
    float4 r;
    r.x = s0.x + s1.x;
    r.y = s0.y + s1.y;
    r.z = s0.z + s1.z;
    r.w = s0.w + s1.w;
    *(float4*)&cat[(size_t)i*CATD + 576 + h*CZD + cc*4] = r;
  }
}

// ---------------- K6: out = cat @ W_out + b_out ----------------
__global__ __launch_bounds__(256) void k_final(const float* __restrict__ Wout,
    float* __restrict__ out, const float* __restrict__ ws) {
  __shared__ float At[64*17];
  __shared__ float Bt[16*64];
  const float* cat = ws + OFF_CAT;
  int t = threadIdx.x;
  int c0 = blockIdx.x*64, r0 = blockIdx.y*64;
  int kstart = blockIdx.z*528;
  float acc[4][4] = {};
  int cc = t & 15, rr = t >> 4;
  for (int kt = 0; kt < 528; kt += 16) {
    int ka = t & 15, mb = t >> 4;
#pragma unroll
    for (int p = 0; p < 4; ++p) {
      int m = mb + p*16;
      At[m*17 + ka] = cat[(size_t)(r0+m)*CATD + kstart + kt + ka];
    }
    int cb = t & 63, kb = t >> 6;
#pragma unroll
    for (int p = 0; p < 4; ++p) {
      int kk = kb + p*4;
      Bt[kk*64 + cb] = Wout[(size_t)(kstart+kt+kk)*CSD + c0 + cb];
    }
    __syncthreads();
#pragma unroll
    for (int k = 0; k < 16; ++k) {
      float a0 = At[(rr*4+0)*17 + k];
      float a1 = At[(rr*4+1)*17 + k];
      float a2 = At[(rr*4+2)*17 + k];
      float a3 = At[(rr*4+3)*17 + k];
      float4 b4 = *(const float4*)&Bt[k*64 + cc*4];
      acc[0][0] = fmaf(a0,b4.x,acc[0][0]); acc[0][1] = fmaf(a0,b4.y,acc[0][1]);
      acc[0][2] = fmaf(a0,b4.z,acc[0][2]); acc[0][3] = fmaf(a0,b4.w,acc[0][3]);
      acc[1][0] = fmaf(a1,b4.x,acc[1][0]); acc[1][1] = fmaf(a1,b4.y,acc[1][1]);
      acc[1][2] = fmaf(a1,b4.z,acc[1][2]); acc[1][3] = fmaf(a1,b4.w,acc[1][3]);
      acc[2][0] = fmaf(a2,b4.x,acc[2][0]); acc[2][1] = fmaf(a2,b4.y,acc[2][1]);
      acc[2][2] = fmaf(a2,b4.z,acc[2][2]); acc[2][3] = fmaf(a2,b4.w,acc[2][3]);
      acc[3][0] = fmaf(a3,b4.x,acc[3][0]); acc[3][1] = fmaf(a3,b4.y,acc[3][1]);
      acc[3][2] = fmaf(a3,b4.z,acc[3][2]); acc[3][3] = fmaf(a3,b4.w,acc[3][3]);
    }
    __syncthreads();
  }
#pragma unroll
  for (int ii = 0; ii < 4; ++ii)
#pragma unroll
    for (int jj = 0; jj < 4; ++jj)
      atomicAdd(&out[(size_t)(r0+rr*4+ii)*CSD + c0 + cc*4 + jj], acc[ii][jj]);
}

extern "C" void kernel_launch(void* const* d_in, const int* in_sizes, int n_in,
                              void* d_out, int out_size, void* d_ws, size_t ws_size,
                              hipStream_t stream) {
  const float* s    = (const float*)d_in[0];
  const float* z    = (const float*)d_in[1];
  const float* rot  = (const float*)d_in[2];
  const float* trans= (const float*)d_in[3];
  const float* mask = (const float*)d_in[4];
  const float* ss   = (const float*)d_in[5];
  const float* Wq   = (const float*)d_in[6];
  const float* bq   = (const float*)d_in[7];
  const float* Wkv  = (const float*)d_in[8];
  const float* bkv  = (const float*)d_in[9];
  const float* Wqp  = (const float*)d_in[10];
  const float* bqp  = (const float*)d_in[11];
  const float* Wkvp = (const float*)d_in[12];
  const float* bkvp = (const float*)d_in[13];
  const float* Wb   = (const float*)d_in[14];
  const float* bb   = (const float*)d_in[15];
  const float* hw   = (const float*)d_in[16];
  const float* Wout = (const float*)d_in[17];
  const float* bout = (const float*)d_in[18];
  float* ws  = (float*)d_ws;
  float* out = (float*)d_out;

  hipLaunchKernelGGL(k_proj, dim3(18,12), dim3(256), 0, stream,
                     s, Wq,bq, Wkv,bkv, Wqp,bqp, Wkvp,bkvp, ws);
  hipLaunchKernelGGL(k_points, dim3(1728), dim3(256), 0, stream, rot, trans, bout, out, ws);
  hipLaunchKernelGGL(k_bias, dim3(768), dim3(256), 0, stream, z, Wb, bb, ws);
  hipLaunchKernelGGL(k_fused, dim3(768), dim3(256), 0, stream, z, rot, trans, mask, ss, hw, ws);
  hipLaunchKernelGGL(k_final, dim3(6,12,4), dim3(256), 0, stream, Wout, out, ws);
}